// Round 1
// baseline (2320.027 us; speedup 1.0000x reference)
//
#include <hip/hip_runtime.h>
#include <float.h>
#include <math.h>

// Problem constants
#define BB 16
#define LL 400
#define TT 40
#define HH 256
#define EE 256
#define VOCAB 50000
#define NTILES 3128   // vocab tiles of 16 cols (782 groups of 4), 3128*16 = 50048 >= 50000
#define NPW NTILES    // pairs width

typedef __attribute__((ext_vector_type(8))) short bf16x8;
typedef __attribute__((ext_vector_type(4))) float f32x4;
typedef __attribute__((ext_vector_type(8))) unsigned short ushort8;

struct Ctx {
  // inputs
  const float *enc_states, *enc_h, *enc_c, *embed;
  const float *Wih, *Whh, *bih, *bhh;
  const float *Wh_w, *Wh_b, *Ws_w, *Ws_b;
  const float *wc_w, *wc_b, *v_w, *v_b;
  const float *wh_w, *wh_b, *ws_w, *ws_b, *wx_w, *wx_b;
  const float *V_w, *V_b;
  const int *dec_input, *targets, *article_inds;
  const unsigned char *enc_mask;
  // workspace
  float *Gx;        // [T,B,1024]
  float *hs;        // [T,B,256]
  float *dec_proj;  // [T,B,512]
  float *enc_proj;  // [B,L,512]
  float *WihT, *WsT, *WhT;
  float *coverage;  // unused (kept for layout stability)
  float *scores;    // [2][B,L] double-buffered
  unsigned short *hcbA; // [T][96][16][8] bf16 A-fragments of concat(h,ctx), all steps
  float *pairs_m, *pairs_s;  // [640][NPW]
  float *px, *hws;  // [T*B]
  float *pgenA, *attnA;      // [640][16] partials
  float *logitA, *lmA;       // [640]
  int *gidxA;       // [640]
  float *covl_sum;  // [16][16] partials
  unsigned short *hbuf_hi, *hbuf_lo;  // [2][4096] LSTM h exchange
  unsigned *bar;    // LSTM barrier
  unsigned *abar;   // attention group barriers: 16 groups, stride 32 uints
  unsigned short *VF;  // [NTILES][24][4][16][8] bf16 V_w in B-frag order (optional)
  int use_bf16;
  float *out;       // [B]
};

__device__ __forceinline__ float sigf(float x) { return 1.f / (1.f + expf(-x)); }

__device__ __forceinline__ unsigned short f2bf(float x) {
  unsigned u = __builtin_bit_cast(unsigned, x);
  u = (u + 0x7FFFu + ((u >> 16) & 1u)) >> 16;
  return (unsigned short)u;
}
__device__ __forceinline__ float bf2f(unsigned short h) {
  unsigned u = ((unsigned)h) << 16;
  return __builtin_bit_cast(float, u);
}

// ---------------- init ----------------
__global__ void k_init(Ctx c) {
  int i = blockIdx.x * 256 + threadIdx.x;
  if (i == 0) *c.bar = 0u;
  if (i < 512) c.abar[i] = 0u;
  if (i < 640) {
    int t = i >> 4, b = i & 15;
    int tgt = c.targets[b * TT + t];
    c.gidxA[i] = (tgt != 0) ? tgt - 1 : 0;
  }
}

// ---------------- V_w fp32 -> bf16 in MFMA B-frag order ----------------
__global__ void __launch_bounds__(256) k_cvtF(const float* __restrict__ V, unsigned short* __restrict__ VF) {
  __shared__ unsigned short tile[16][800];  // 16 rows x 768 (+pad)
  int nt = blockIdx.x;          // 0..NTILES-1
  int tid = threadIdx.x;        // 256
  for (int u = tid; u < 3072; u += 256) {
    int rr = u / 192, cc = u % 192;
    int v = nt * 16 + rr;
    float4 x = {0.f, 0.f, 0.f, 0.f};
    if (v < VOCAB) x = ((const float4*)(V + (size_t)v * 768))[cc];
    unsigned short* d = &tile[rr][cc * 4];
    d[0] = f2bf(x.x); d[1] = f2bf(x.y); d[2] = f2bf(x.z); d[3] = f2bf(x.w);
  }
  __syncthreads();
  ushort8* dst = (ushort8*)(VF + (size_t)nt * 12288);
  for (int u = tid; u < 1536; u += 256) {
    int n = u & 15, kq = u >> 4;
    const unsigned short* s = &tile[n][kq * 8];
    ushort8 o;
#pragma unroll
    for (int j = 0; j < 8; ++j) o[j] = s[j];
    dst[u] = o;
  }
}

// ---------------- tiled transpose: in[R][C] -> out[C][R] ----------------
__global__ void k_transpose(const float* __restrict__ in, float* __restrict__ out, int R, int C) {
  __shared__ float tile[32][33];
  int bx = blockIdx.x * 32, by = blockIdx.y * 32;
  int tx = threadIdx.x, ty = threadIdx.y;
  for (int i = ty; i < 32; i += 8) tile[i][tx] = in[(by + i) * C + bx + tx];
  __syncthreads();
  for (int i = ty; i < 32; i += 8) out[(bx + i) * R + by + tx] = tile[tx][i];
}

// ---------------- Gx = embed[dec_input] @ Wih^T + bih + bhh ; px = e.wx ----------------
__global__ void k_gx(Ctx c) {
  int tb = blockIdx.x;
  int t = tb >> 4, b = tb & 15;
  int tid = threadIdx.x;          // 256
  __shared__ float x[EE];
  __shared__ float red[256];
  int tok = c.dec_input[b * TT + t];
  x[tid] = c.embed[(size_t)tok * EE + tid];
  __syncthreads();
  const float4* WT4 = (const float4*)c.WihT;
  float4 acc = ((const float4*)c.bih)[tid];
  float4 b2 = ((const float4*)c.bhh)[tid];
  acc.x += b2.x; acc.y += b2.y; acc.z += b2.z; acc.w += b2.w;
#pragma unroll 4
  for (int k = 0; k < EE; ++k) {
    float xv = x[k];
    float4 w = WT4[k * 256 + tid];
    acc.x += xv * w.x; acc.y += xv * w.y; acc.z += xv * w.z; acc.w += xv * w.w;
  }
  ((float4*)c.Gx)[tb * 256 + tid] = acc;
  red[tid] = x[tid] * c.wx_w[tid];
  __syncthreads();
  for (int s = 128; s > 0; s >>= 1) { if (tid < s) red[tid] += red[tid + s]; __syncthreads(); }
  if (tid == 0) c.px[tb] = red[0];
}

// ---------------- persistent MFMA LSTM: 16 WGs, Whh split-bf16 in VGPRs ----------------
__global__ void __launch_bounds__(256) k_lstm(Ctx c) {
  __shared__ unsigned short hAhi[4096], hAlo[4096];
  __shared__ float gs[4][16][16];
  int w = blockIdx.x, tid = threadIdx.x;
  int g = tid >> 6, lane = tid & 63;
  int n = lane & 15, q = lane >> 4;
  bf16x8 Bhi[8], Blo[8];
  {
    const float* wr = c.Whh + (size_t)(g * 256 + w * 16 + n) * 256;
#pragma unroll
    for (int kc = 0; kc < 8; ++kc) {
      const float* p8 = wr + kc * 32 + q * 8;
#pragma unroll
      for (int j = 0; j < 8; ++j) {
        float x = p8[j];
        unsigned short hi = f2bf(x);
        unsigned short lo = f2bf(x - bf2f(hi));
        Bhi[kc][j] = (short)hi; Blo[kc][j] = (short)lo;
      }
    }
  }
  for (int idx = tid; idx < 4096; idx += 256) {
    int b = idx >> 8, k = idx & 255;
    float x = c.enc_h[idx];
    unsigned short hi = f2bf(x);
    unsigned short lo = f2bf(x - bf2f(hi));
    int pos = (((k >> 5) * 4 + ((k >> 3) & 3)) * 16 + b) * 8 + (k & 7);
    hAhi[pos] = hi; hAlo[pos] = lo;
  }
  int bu = tid >> 4, ju = tid & 15;
  float creg = c.enc_c[bu * 256 + w * 16 + ju];
  __syncthreads();
  const bf16x8* Ahi = (const bf16x8*)hAhi;
  const bf16x8* Alo = (const bf16x8*)hAlo;
  int col = g * 256 + w * 16 + n;
  for (int t = 0; t < TT; ++t) {
    const float* gxp = c.Gx + (size_t)(t * 16) * 1024 + col;
    f32x4 acc;
    acc[0] = gxp[(q * 4 + 0) * 1024]; acc[1] = gxp[(q * 4 + 1) * 1024];
    acc[2] = gxp[(q * 4 + 2) * 1024]; acc[3] = gxp[(q * 4 + 3) * 1024];
#pragma unroll
    for (int kc = 0; kc < 8; ++kc) {
      bf16x8 ah = Ahi[(kc * 4 + q) * 16 + n];
      bf16x8 al = Alo[(kc * 4 + q) * 16 + n];
      acc = __builtin_amdgcn_mfma_f32_16x16x32_bf16(ah, Bhi[kc], acc, 0, 0, 0);
      acc = __builtin_amdgcn_mfma_f32_16x16x32_bf16(al, Bhi[kc], acc, 0, 0, 0);
      acc = __builtin_amdgcn_mfma_f32_16x16x32_bf16(ah, Blo[kc], acc, 0, 0, 0);
    }
#pragma unroll
    for (int r = 0; r < 4; ++r) gs[g][q * 4 + r][n] = acc[r];
    __syncthreads();
    {
      float ig = gs[0][bu][ju], fg = gs[1][bu][ju], gg = gs[2][bu][ju], og = gs[3][bu][ju];
      creg = sigf(fg) * creg + sigf(ig) * tanhf(gg);
      float hv = sigf(og) * tanhf(creg);
      int j = w * 16 + ju;
      c.hs[(t * 16 + bu) * 256 + j] = hv;
      unsigned short hi = f2bf(hv);
      unsigned short lo = f2bf(hv - bf2f(hi));
      int pos = (((j >> 5) * 4 + ((j >> 3) & 3)) * 16 + bu) * 8 + (j & 7);
      int par = (t + 1) & 1;
      c.hbuf_hi[par * 4096 + pos] = hi;
      c.hbuf_lo[par * 4096 + pos] = lo;
    }
    __threadfence();
    __syncthreads();
    if (tid == 0) {
      __hip_atomic_fetch_add(c.bar, 1u, __ATOMIC_ACQ_REL, __HIP_MEMORY_SCOPE_AGENT);
      while (__hip_atomic_load(c.bar, __ATOMIC_ACQUIRE, __HIP_MEMORY_SCOPE_AGENT) < (unsigned)(16 * (t + 1)))
        __builtin_amdgcn_s_sleep(2);
      __threadfence();
    }
    __syncthreads();
    if (t < TT - 1) {
      int par = (t + 1) & 1;
      for (int idx = tid; idx < 4096; idx += 256) {
        hAhi[idx] = c.hbuf_hi[par * 4096 + idx];
        hAlo[idx] = c.hbuf_lo[par * 4096 + idx];
      }
      __syncthreads();
    }
  }
}

// ---------------- dec_proj = hs @ Ws^T + Ws_b ; hws = h.ws ----------------
__global__ void k_decproj(Ctx c) {
  int tb = blockIdx.x, tid = threadIdx.x;  // block 512
  __shared__ float h[256];
  __shared__ float red[256];
  if (tid < 256) h[tid] = c.hs[tb * 256 + tid];
  __syncthreads();
  float acc = c.Ws_b[tid];
#pragma unroll 4
  for (int k = 0; k < 256; ++k) acc += h[k] * c.WsT[k * 512 + tid];
  c.dec_proj[tb * 512 + tid] = acc;
  if (tid < 256) red[tid] = h[tid] * c.ws_w[tid];
  __syncthreads();
  for (int s = 128; s > 0; s >>= 1) { if (tid < 256 && tid < s) red[tid] += red[tid + s]; __syncthreads(); }
  if (tid == 0) c.hws[tb] = red[0];
}

// ---------------- enc_proj = enc_states @ Wh^T + Wh_b ----------------
__global__ void k_encproj(Ctx c) {
  int b = blockIdx.x / 100, lt = (blockIdx.x % 100) * 4, tid = threadIdx.x; // block 512
  __shared__ float es[4][512];
  for (int i = 0; i < 4; ++i) es[i][tid] = c.enc_states[(size_t)(b * LL + lt + i) * 512 + tid];
  __syncthreads();
  float bias = c.Wh_b[tid];
  float a0 = bias, a1 = bias, a2 = bias, a3 = bias;
#pragma unroll 4
  for (int k = 0; k < 512; ++k) {
    float w = c.WhT[k * 512 + tid];
    a0 += es[0][k] * w; a1 += es[1][k] * w; a2 += es[2][k] * w; a3 += es[3][k] * w;
  }
  c.enc_proj[(size_t)(b * LL + lt + 0) * 512 + tid] = a0;
  c.enc_proj[(size_t)(b * LL + lt + 1) * 512 + tid] = a1;
  c.enc_proj[(size_t)(b * LL + lt + 2) * 512 + tid] = a2;
  c.enc_proj[(size_t)(b * LL + lt + 3) * 512 + tid] = a3;
}

// ---------------- persistent fused attention loop ----------------
// 16 groups (one per batch row b) x 16 blocks x 256 threads.
// Each block owns l-slice [blk*25, blk*25+25). Recurrence (coverage) is
// per-b only -> group-scoped barrier, ONE per t (double-buffered scores).
// enc_proj slice + attention consts live in LDS for all 40 steps.
__global__ void __launch_bounds__(256, 1) k_attn(Ctx c) {
  __shared__ float ep_s[25 * 512];           // 51.2 KB, resident all t
  __shared__ float wcw_s[512], wcb_s[512], vw_s[512], dp_s[512];
  __shared__ float attn_s[400];
  __shared__ float red[256];
  __shared__ float ctxred[8][32];
  __shared__ float cov_s[25];
  __shared__ int idx_s[25];
  __shared__ unsigned char msk_s[32];
  int tid = threadIdx.x;
  int b = blockIdx.x >> 4;     // group = batch row
  int blk = blockIdx.x & 15;   // block within group
  int l0 = blk * 25;
  int wv = tid >> 6, lane = tid & 63;
  const float* epb = c.enc_proj + ((size_t)b * LL + l0) * 512;
  const float* esb = c.enc_states + (size_t)b * LL * 512;
  for (int i = tid; i < 12800; i += 256) ep_s[i] = epb[i];
  wcw_s[tid] = c.wc_w[tid]; wcw_s[tid + 256] = c.wc_w[tid + 256];
  wcb_s[tid] = c.wc_b[tid]; wcb_s[tid + 256] = c.wc_b[tid + 256];
  vw_s[tid]  = c.v_w[tid];  vw_s[tid + 256]  = c.v_w[tid + 256];
  if (tid < 25) {
    cov_s[tid] = 0.f;
    unsigned char m = c.enc_mask[b * LL + l0 + tid];
    msk_s[tid] = m;
    idx_s[tid] = m ? 0 : (c.article_inds[b * LL + l0 + tid] - 1);
  }
  float covl_loc = 0.f;
  float vb = c.v_b[0];
  unsigned* barp = c.abar + b * 32;   // own cache line per group
  __syncthreads();
  for (int t = 0; t < TT; ++t) {
    // stage dec_proj row for this t
    const float* dp = c.dec_proj + (size_t)(t * 16 + b) * 512;
    dp_s[tid] = dp[tid]; dp_s[tid + 256] = dp[tid + 256];
    __syncthreads();
    // ---- phase A: scores for own 25 l's (all-LDS operands) ----
    float* sb = c.scores + (t & 1) * (BB * LL) + b * LL;
    for (int li = wv; li < 25; li += 4) {
      float cov = cov_s[li];
      const float* ep = ep_s + li * 512;
      float acc = 0.f;
#pragma unroll
      for (int i = 0; i < 8; ++i) {
        int j = lane + 64 * i;
        float f = ep[j] + dp_s[j] + cov * wcw_s[j] + wcb_s[j];
        acc += tanhf(f) * vw_s[j];
      }
      for (int off = 1; off < 64; off <<= 1) acc += __shfl_xor(acc, off, 64);
      if (lane == 0) sb[l0 + li] = msk_s[li] ? -1e30f : (acc + vb);
    }
    // ---- group barrier (scores(t) complete across 16 blocks) ----
    __threadfence();
    __syncthreads();
    if (tid == 0) {
      __hip_atomic_fetch_add(barp, 1u, __ATOMIC_ACQ_REL, __HIP_MEMORY_SCOPE_AGENT);
      while (__hip_atomic_load(barp, __ATOMIC_ACQUIRE, __HIP_MEMORY_SCOPE_AGENT) < 16u * (unsigned)(t + 1))
        __builtin_amdgcn_s_sleep(2);
      __threadfence();
    }
    __syncthreads();
    // ---- phase B: softmax over 400 (redundant, identical order per block) ----
    float v0 = (tid < 400) ? sb[tid] : -FLT_MAX;
    float v1 = (tid + 256 < 400) ? sb[tid + 256] : -FLT_MAX;
    red[tid] = fmaxf(v0, v1);
    __syncthreads();
    for (int s = 128; s > 0; s >>= 1) { if (tid < s) red[tid] = fmaxf(red[tid], red[tid + s]); __syncthreads(); }
    float M = red[0]; __syncthreads();
    float e0 = (tid < 400) ? __expf(v0 - M) : 0.f;
    float e1 = (tid + 256 < 400) ? __expf(v1 - M) : 0.f;
    red[tid] = e0 + e1;
    __syncthreads();
    for (int s = 128; s > 0; s >>= 1) { if (tid < s) red[tid] += red[tid + s]; __syncthreads(); }
    float S = red[0]; __syncthreads();
    if (tid < 400) attn_s[tid] = e0 / S;
    if (tid + 256 < 400) attn_s[tid + 256] = e1 / S;
    __syncthreads();
    // coverage + covl + mct on own l's (wave 0, lanes 0..24)
    if (wv == 0) {
      float cvl = 0.f, mct = 0.f;
      if (lane < 25) {
        float a = attn_s[l0 + lane];
        float nc = cov_s[lane] + a;
        cov_s[lane] = nc;
        cvl = fminf(nc, a);
        int tgt = c.targets[b * TT + t];
        int gidx = (tgt != 0) ? tgt - 1 : 0;
        mct = (idx_s[lane] == gidx) ? a : 0.f;
      }
      for (int off = 1; off < 32; off <<= 1) {
        cvl += __shfl_xor(cvl, off, 32);
        mct += __shfl_xor(mct, off, 32);
      }
      if (lane == 0) {
        covl_loc += cvl;
        c.attnA[(size_t)(t * 16 + b) * 16 + blk] = mct;
      }
    }
    // context partial: this block's 32 e-cols over all 400 l (L2 reads)
    {
      int e = tid & 31, lc = tid >> 5;
      const float* esc = esb + blk * 32 + e;
      float part = 0.f;
      int lbeg = lc * 50;
#pragma unroll 10
      for (int l = lbeg; l < lbeg + 50; ++l) part += attn_s[l] * esc[(size_t)l * 512];
      ctxred[lc][e] = part;
    }
    // h-part of hcbA: one block per group writes it
    if (blk == 0) {
      float hv = c.hs[(size_t)(t * 16 + b) * 256 + tid];
      c.hcbA[(size_t)t * 12288 + (tid >> 3) * 128 + b * 8 + (tid & 7)] = f2bf(hv);
    }
    __syncthreads();
    if (tid < 32) {
      float cx = 0.f;
#pragma unroll
      for (int r = 0; r < 8; ++r) cx += ctxred[r][tid];
      int jj = 256 + blk * 32 + tid;
      c.hcbA[(size_t)t * 12288 + (jj >> 3) * 128 + b * 8 + (jj & 7)] = f2bf(cx);
      float pp = cx * c.wh_w[blk * 32 + tid];
      for (int off = 1; off < 32; off <<= 1) pp += __shfl_xor(pp, off, 32);
      if (tid == 0) c.pgenA[(size_t)(t * 16 + b) * 16 + blk] = pp;
    }
    __syncthreads();  // protect cov_s / dp_s / attn_s reuse at next t
  }
  if (tid == 0) c.covl_sum[b * 16 + blk] = covl_loc;
}

// ---------------- one-shot vocab GEMM, barrier-free, LDS-free ----------------
__global__ void __launch_bounds__(256, 4) k_vocab_all(Ctx c) {
  int tid = threadIdx.x;
  int wv = tid >> 6, lane = tid & 63;
  int n = lane & 15, q = lane >> 4;
  int cg = blockIdx.x >> 2, tg = blockIdx.x & 3;
  int nt = cg * 4 + wv;
  int col = nt * 16 + n;
  bool vld = col < VOCAB;
  int colc = vld ? col : VOCAB - 1;
  float vb = c.V_b[colc];
  int t0 = tg * 10;
  f32x4 D[10];
#pragma unroll
  for (int i = 0; i < 10; ++i) D[i] = (f32x4){0.f, 0.f, 0.f, 0.f};
  const bf16x8* A8 = (const bf16x8*)c.hcbA;
  size_t abase = ((size_t)t0 * 96) * 16 + q * 16 + n;   // + i*1536 + kc*64
  if (c.use_bf16) {
    const bf16x8* BF = (const bf16x8*)c.VF;
    size_t bbase = (size_t)nt * 1536 + q * 16 + n;      // + kc*64
    for (int kc = 0; kc < 24; ++kc) {
      bf16x8 B = BF[bbase + kc * 64];
#pragma unroll
      for (int i = 0; i < 10; ++i) {
        bf16x8 a = A8[abase + (size_t)i * 1536 + kc * 64];
        D[i] = __builtin_amdgcn_mfma_f32_16x16x32_bf16(a, B, D[i], 0, 0, 0);
      }
    }
  } else {
    for (int kc = 0; kc < 24; ++kc) {
      const float4* vr = (const float4*)(c.V_w + (size_t)colc * 768 + kc * 32 + q * 8);
      float4 b0 = vr[0], b1 = vr[1];
      bf16x8 B;
      B[0] = (short)f2bf(b0.x); B[1] = (short)f2bf(b0.y); B[2] = (short)f2bf(b0.z); B[3] = (short)f2bf(b0.w);
      B[4] = (short)f2bf(b1.x); B[5] = (short)f2bf(b1.y); B[6] = (short)f2bf(b1.z); B[7] = (short)f2bf(b1.w);
#pragma unroll
      for (int i = 0; i < 10; ++i) {
        bf16x8 a = A8[abase + (size_t)i * 1536 + kc * 64];
        D[i] = __builtin_amdgcn_mfma_f32_16x16x32_bf16(a, B, D[i], 0, 0, 0);
      }
    }
  }
#pragma unroll
  for (int i = 0; i < 10; ++i) {
    int t = t0 + i;
#pragma unroll
    for (int r = 0; r < 4; ++r) {
      int b = q * 4 + r;
      int rw = t * 16 + b;
      float lg = D[i][r] + vb;
      if (vld && col == c.gidxA[rw]) c.logitA[rw] = lg;
      float m_ = vld ? lg : -FLT_MAX;
      float s_ = vld ? 1.f : 0.f;
#pragma unroll
      for (int off = 1; off < 16; off <<= 1) {
        float om = __shfl_xor(m_, off, 16);
        float os = __shfl_xor(s_, off, 16);
        float Mm = fmaxf(m_, om);
        s_ = s_ * __expf(m_ - Mm) + os * __expf(om - Mm);
        m_ = Mm;
      }
      if (n == 0) {
        c.pairs_m[(size_t)rw * NPW + nt] = m_;
        c.pairs_s[(size_t)rw * NPW + nt] = s_;
      }
    }
  }
}

// ---------------- per-(t,b) loss from pairs ----------------
__global__ void k_final_all(Ctx c) {
  int row = blockIdx.x;  // t*16 + b
  int tid = threadIdx.x; // 256
  __shared__ float red[256];
  float m = -FLT_MAX;
  for (int i = tid; i < NPW; i += 256) m = fmaxf(m, c.pairs_m[(size_t)row * NPW + i]);
  red[tid] = m; __syncthreads();
  for (int s = 128; s > 0; s >>= 1) { if (tid < s) red[tid] = fmaxf(red[tid], red[tid + s]); __syncthreads(); }
  float M = red[0]; __syncthreads();
  float z = 0.f;
  for (int i = tid; i < NPW; i += 256)
    z += c.pairs_s[(size_t)row * NPW + i] * __expf(c.pairs_m[(size_t)row * NPW + i] - M);
  red[tid] = z; __syncthreads();
  for (int s = 128; s > 0; s >>= 1) { if (tid < s) red[tid] += red[tid + s]; __syncthreads(); }
  if (tid == 0) {
    int t = row >> 4, b = row & 15;
    int tgt = c.targets[b * TT + t];
    float lm = 0.f;
    if (tgt != 0) {
      float pgs = 0.f, ats = 0.f;
#pragma unroll
      for (int i = 0; i < 16; ++i) {
        pgs += c.pgenA[(size_t)row * 16 + i];
        ats += c.attnA[(size_t)row * 16 + i];
      }
      float pg = sigf(pgs + c.wh_b[0] + c.hws[row] + c.ws_b[0] + c.px[row] + c.wx_b[0]);
      float p = __expf(c.logitA[row] - M) / red[0];
      lm = -logf(pg * p + (1.f - pg) * ats);
    }
    c.lmA[row] = lm;
  }
}

// ---------------- output ----------------
__global__ void k_out(Ctx c) {
  int b = blockIdx.x, tid = threadIdx.x; // 64 threads
  float lm = (tid < TT) ? c.lmA[tid * 16 + b] : 0.f;
  float dl = (tid < TT && c.dec_input[b * TT + tid] > 0) ? 1.f : 0.f;
  float cv = (tid < 16) ? c.covl_sum[b * 16 + tid] : 0.f;
  for (int off = 1; off < 64; off <<= 1) {
    lm += __shfl_xor(lm, off, 64);
    dl += __shfl_xor(dl, off, 64);
    cv += __shfl_xor(cv, off, 64);
  }
  if (tid == 0) c.out[b] = lm / dl + cv / dl;
}

extern "C" void kernel_launch(void* const* d_in, const int* in_sizes, int n_in,
                              void* d_out, int out_size, void* d_ws, size_t ws_size,
                              hipStream_t stream) {
  Ctx c;
  c.enc_states = (const float*)d_in[0];
  c.enc_h      = (const float*)d_in[1];
  c.enc_c      = (const float*)d_in[2];
  c.embed      = (const float*)d_in[3];
  c.Wih        = (const float*)d_in[4];
  c.Whh        = (const float*)d_in[5];
  c.bih        = (const float*)d_in[6];
  c.bhh        = (const float*)d_in[7];
  c.Wh_w       = (const float*)d_in[8];
  c.Wh_b       = (const float*)d_in[9];
  c.Ws_w       = (const float*)d_in[10];
  c.Ws_b       = (const float*)d_in[11];
  c.wc_w       = (const float*)d_in[12];
  c.wc_b       = (const float*)d_in[13];
  c.v_w        = (const float*)d_in[14];
  c.v_b        = (const float*)d_in[15];
  c.wh_w       = (const float*)d_in[16];
  c.wh_b       = (const float*)d_in[17];
  c.ws_w       = (const float*)d_in[18];
  c.ws_b       = (const float*)d_in[19];
  c.wx_w       = (const float*)d_in[20];
  c.wx_b       = (const float*)d_in[21];
  c.V_w        = (const float*)d_in[22];
  c.V_b        = (const float*)d_in[23];
  c.dec_input  = (const int*)d_in[24];
  c.targets    = (const int*)d_in[25];
  c.article_inds = (const int*)d_in[26];
  c.enc_mask   = (const unsigned char*)d_in[27];

  float* p = (float*)d_ws;
  c.Gx = p;        p += TT * BB * 1024;
  c.hs = p;        p += TT * BB * 256;
  c.dec_proj = p;  p += TT * BB * 512;
  c.enc_proj = p;  p += (size_t)BB * LL * 512;
  c.WihT = p;      p += 1024 * 256;
  c.WsT = p;       p += 512 * 256;
  c.WhT = p;       p += 512 * 512;
  c.coverage = p;  p += BB * LL;
  c.scores = p;    p += 2 * BB * LL;
  c.hcbA = (unsigned short*)p; p += TT * BB * 768 / 2;
  c.pairs_m = p;   p += (size_t)640 * NPW;
  c.pairs_s = p;   p += (size_t)640 * NPW;
  c.px = p;        p += TT * BB;
  c.hws = p;       p += TT * BB;
  c.pgenA = p;     p += 640 * 16;
  c.attnA = p;     p += 640 * 16;
  c.logitA = p;    p += 640;
  c.lmA = p;       p += 640;
  c.gidxA = (int*)p; p += 640;
  c.covl_sum = p;  p += 256;
  c.hbuf_hi = (unsigned short*)p; p += 2 * 4096 / 2;
  c.hbuf_lo = (unsigned short*)p; p += 2 * 4096 / 2;
  c.bar = (unsigned*)p; p += 16;
  c.abar = (unsigned*)p; p += 512;   // 16 groups * 32-uint stride
  c.VF = (unsigned short*)p;
  size_t used_bytes = (size_t)((char*)p - (char*)d_ws);
  size_t vf_bytes = (size_t)NTILES * 12288 * 2;
  c.use_bf16 = (used_bytes + vf_bytes <= ws_size) ? 1 : 0;
  c.out = (float*)d_out;

  k_init<<<3, 256, 0, stream>>>(c);
  if (c.use_bf16) k_cvtF<<<NTILES, 256, 0, stream>>>(c.V_w, c.VF);
  k_transpose<<<dim3(8, 32), dim3(32, 8), 0, stream>>>(c.Wih, c.WihT, 1024, 256);
  k_transpose<<<dim3(8, 16), dim3(32, 8), 0, stream>>>(c.Ws_w, c.WsT, 512, 256);
  k_transpose<<<dim3(16, 16), dim3(32, 8), 0, stream>>>(c.Wh_w, c.WhT, 512, 512);
  k_gx<<<TT * BB, 256, 0, stream>>>(c);
  k_encproj<<<16 * 100, 512, 0, stream>>>(c);
  k_lstm<<<16, 256, 0, stream>>>(c);
  k_decproj<<<TT * BB, 512, 0, stream>>>(c);
  k_attn<<<256, 256, 0, stream>>>(c);
  k_vocab_all<<<782 * 4, 256, 0, stream>>>(c);
  k_final_all<<<640, 256, 0, stream>>>(c);
  k_out<<<16, 64, 0, stream>>>(c);
}

// Round 2
// 1410.375 us; speedup vs baseline: 1.6450x; 1.6450x over previous
//
#include <hip/hip_runtime.h>
#include <float.h>
#include <math.h>

// Problem constants
#define BB 16
#define LL 400
#define TT 40
#define HH 256
#define EE 256
#define VOCAB 50000
#define NTILES 3128   // vocab tiles of 16 cols (782 groups of 4), 3128*16 = 50048 >= 50000
#define NPW NTILES    // pairs width

typedef __attribute__((ext_vector_type(8))) short bf16x8;
typedef __attribute__((ext_vector_type(4))) float f32x4;
typedef __attribute__((ext_vector_type(8))) unsigned short ushort8;

struct Ctx {
  // inputs
  const float *enc_states, *enc_h, *enc_c, *embed;
  const float *Wih, *Whh, *bih, *bhh;
  const float *Wh_w, *Wh_b, *Ws_w, *Ws_b;
  const float *wc_w, *wc_b, *v_w, *v_b;
  const float *wh_w, *wh_b, *ws_w, *ws_b, *wx_w, *wx_b;
  const float *V_w, *V_b;
  const int *dec_input, *targets, *article_inds;
  const unsigned char *enc_mask;
  // workspace
  float *Gx;        // [T,B,1024]
  float *hs;        // [T,B,256]
  float *dec_proj;  // [T,B,512]
  float *enc_proj;  // [B,L,512]
  float *WihT, *WsT, *WhT;
  float *coverage;  // unused (layout stability)
  float *scores;    // unused (layout stability)
  unsigned short *hcbA; // [T][96][16][8] bf16 A-fragments of concat(h,ctx), all steps
  float *pairs_m, *pairs_s;  // [640][NPW]
  float *px, *hws;  // [T*B]
  float *pgenA, *attnA;      // [640][16] partials
  float *logitA, *lmA;       // [640]
  int *gidxA;       // [640]
  float *covl_sum;  // [16][16] partials
  unsigned short *hbuf_hi, *hbuf_lo;  // [2][4096] LSTM h exchange
  unsigned *bar;    // LSTM barrier
  unsigned *abar;   // attention group barriers: 16 groups, stride 32 uints
  float *xm, *xs;   // [2][16][16] per-block softmax partials (m, sum)
  float *xpc;       // [2][16][16][512] per-block unnormalized partial context
  unsigned short *VF;  // [NTILES][24][4][16][8] bf16 V_w in B-frag order (optional)
  int use_bf16;
  float *out;       // [B]
};

__device__ __forceinline__ float sigf(float x) { return 1.f / (1.f + expf(-x)); }

__device__ __forceinline__ unsigned short f2bf(float x) {
  unsigned u = __builtin_bit_cast(unsigned, x);
  u = (u + 0x7FFFu + ((u >> 16) & 1u)) >> 16;
  return (unsigned short)u;
}
__device__ __forceinline__ float bf2f(unsigned short h) {
  unsigned u = ((unsigned)h) << 16;
  return __builtin_bit_cast(float, u);
}

// coherent (sc1, L2-bypass) helpers: relaxed agent-scope atomics -> no cache
// maintenance ops, no L2 pollution, always fresh across XCDs.
__device__ __forceinline__ void cstore(float* p, float v) {
  __hip_atomic_store(p, v, __ATOMIC_RELAXED, __HIP_MEMORY_SCOPE_AGENT);
}
__device__ __forceinline__ float cload(const float* p) {
  return __hip_atomic_load(p, __ATOMIC_RELAXED, __HIP_MEMORY_SCOPE_AGENT);
}

// ---------------- init ----------------
__global__ void k_init(Ctx c) {
  int i = blockIdx.x * 256 + threadIdx.x;
  if (i == 0) *c.bar = 0u;
  if (i < 512) c.abar[i] = 0u;
  if (i < 640) {
    int t = i >> 4, b = i & 15;
    int tgt = c.targets[b * TT + t];
    c.gidxA[i] = (tgt != 0) ? tgt - 1 : 0;
  }
}

// ---------------- V_w fp32 -> bf16 in MFMA B-frag order ----------------
__global__ void __launch_bounds__(256) k_cvtF(const float* __restrict__ V, unsigned short* __restrict__ VF) {
  __shared__ unsigned short tile[16][800];  // 16 rows x 768 (+pad)
  int nt = blockIdx.x;          // 0..NTILES-1
  int tid = threadIdx.x;        // 256
  for (int u = tid; u < 3072; u += 256) {
    int rr = u / 192, cc = u % 192;
    int v = nt * 16 + rr;
    float4 x = {0.f, 0.f, 0.f, 0.f};
    if (v < VOCAB) x = ((const float4*)(V + (size_t)v * 768))[cc];
    unsigned short* d = &tile[rr][cc * 4];
    d[0] = f2bf(x.x); d[1] = f2bf(x.y); d[2] = f2bf(x.z); d[3] = f2bf(x.w);
  }
  __syncthreads();
  ushort8* dst = (ushort8*)(VF + (size_t)nt * 12288);
  for (int u = tid; u < 1536; u += 256) {
    int n = u & 15, kq = u >> 4;
    const unsigned short* s = &tile[n][kq * 8];
    ushort8 o;
#pragma unroll
    for (int j = 0; j < 8; ++j) o[j] = s[j];
    dst[u] = o;
  }
}

// ---------------- tiled transpose: in[R][C] -> out[C][R] ----------------
__global__ void k_transpose(const float* __restrict__ in, float* __restrict__ out, int R, int C) {
  __shared__ float tile[32][33];
  int bx = blockIdx.x * 32, by = blockIdx.y * 32;
  int tx = threadIdx.x, ty = threadIdx.y;
  for (int i = ty; i < 32; i += 8) tile[i][tx] = in[(by + i) * C + bx + tx];
  __syncthreads();
  for (int i = ty; i < 32; i += 8) out[(bx + i) * R + by + tx] = tile[tx][i];
}

// ---------------- Gx = embed[dec_input] @ Wih^T + bih + bhh ; px = e.wx ----------------
__global__ void k_gx(Ctx c) {
  int tb = blockIdx.x;
  int t = tb >> 4, b = tb & 15;
  int tid = threadIdx.x;          // 256
  __shared__ float x[EE];
  __shared__ float red[256];
  int tok = c.dec_input[b * TT + t];
  x[tid] = c.embed[(size_t)tok * EE + tid];
  __syncthreads();
  const float4* WT4 = (const float4*)c.WihT;
  float4 acc = ((const float4*)c.bih)[tid];
  float4 b2 = ((const float4*)c.bhh)[tid];
  acc.x += b2.x; acc.y += b2.y; acc.z += b2.z; acc.w += b2.w;
#pragma unroll 4
  for (int k = 0; k < EE; ++k) {
    float xv = x[k];
    float4 w = WT4[k * 256 + tid];
    acc.x += xv * w.x; acc.y += xv * w.y; acc.z += xv * w.z; acc.w += xv * w.w;
  }
  ((float4*)c.Gx)[tb * 256 + tid] = acc;
  red[tid] = x[tid] * c.wx_w[tid];
  __syncthreads();
  for (int s = 128; s > 0; s >>= 1) { if (tid < s) red[tid] += red[tid + s]; __syncthreads(); }
  if (tid == 0) c.px[tb] = red[0];
}

// ---------------- persistent MFMA LSTM: 16 WGs, Whh split-bf16 in VGPRs ----------------
__global__ void __launch_bounds__(256) k_lstm(Ctx c) {
  __shared__ unsigned short hAhi[4096], hAlo[4096];
  __shared__ float gs[4][16][16];
  int w = blockIdx.x, tid = threadIdx.x;
  int g = tid >> 6, lane = tid & 63;
  int n = lane & 15, q = lane >> 4;
  bf16x8 Bhi[8], Blo[8];
  {
    const float* wr = c.Whh + (size_t)(g * 256 + w * 16 + n) * 256;
#pragma unroll
    for (int kc = 0; kc < 8; ++kc) {
      const float* p8 = wr + kc * 32 + q * 8;
#pragma unroll
      for (int j = 0; j < 8; ++j) {
        float x = p8[j];
        unsigned short hi = f2bf(x);
        unsigned short lo = f2bf(x - bf2f(hi));
        Bhi[kc][j] = (short)hi; Blo[kc][j] = (short)lo;
      }
    }
  }
  for (int idx = tid; idx < 4096; idx += 256) {
    int b = idx >> 8, k = idx & 255;
    float x = c.enc_h[idx];
    unsigned short hi = f2bf(x);
    unsigned short lo = f2bf(x - bf2f(hi));
    int pos = (((k >> 5) * 4 + ((k >> 3) & 3)) * 16 + b) * 8 + (k & 7);
    hAhi[pos] = hi; hAlo[pos] = lo;
  }
  int bu = tid >> 4, ju = tid & 15;
  float creg = c.enc_c[bu * 256 + w * 16 + ju];
  __syncthreads();
  const bf16x8* Ahi = (const bf16x8*)hAhi;
  const bf16x8* Alo = (const bf16x8*)hAlo;
  int col = g * 256 + w * 16 + n;
  for (int t = 0; t < TT; ++t) {
    const float* gxp = c.Gx + (size_t)(t * 16) * 1024 + col;
    f32x4 acc;
    acc[0] = gxp[(q * 4 + 0) * 1024]; acc[1] = gxp[(q * 4 + 1) * 1024];
    acc[2] = gxp[(q * 4 + 2) * 1024]; acc[3] = gxp[(q * 4 + 3) * 1024];
#pragma unroll
    for (int kc = 0; kc < 8; ++kc) {
      bf16x8 ah = Ahi[(kc * 4 + q) * 16 + n];
      bf16x8 al = Alo[(kc * 4 + q) * 16 + n];
      acc = __builtin_amdgcn_mfma_f32_16x16x32_bf16(ah, Bhi[kc], acc, 0, 0, 0);
      acc = __builtin_amdgcn_mfma_f32_16x16x32_bf16(al, Bhi[kc], acc, 0, 0, 0);
      acc = __builtin_amdgcn_mfma_f32_16x16x32_bf16(ah, Blo[kc], acc, 0, 0, 0);
    }
#pragma unroll
    for (int r = 0; r < 4; ++r) gs[g][q * 4 + r][n] = acc[r];
    __syncthreads();
    {
      float ig = gs[0][bu][ju], fg = gs[1][bu][ju], gg = gs[2][bu][ju], og = gs[3][bu][ju];
      creg = sigf(fg) * creg + sigf(ig) * tanhf(gg);
      float hv = sigf(og) * tanhf(creg);
      int j = w * 16 + ju;
      c.hs[(t * 16 + bu) * 256 + j] = hv;
      unsigned short hi = f2bf(hv);
      unsigned short lo = f2bf(hv - bf2f(hi));
      int pos = (((j >> 5) * 4 + ((j >> 3) & 3)) * 16 + bu) * 8 + (j & 7);
      int par = (t + 1) & 1;
      c.hbuf_hi[par * 4096 + pos] = hi;
      c.hbuf_lo[par * 4096 + pos] = lo;
    }
    __threadfence();
    __syncthreads();
    if (tid == 0) {
      __hip_atomic_fetch_add(c.bar, 1u, __ATOMIC_ACQ_REL, __HIP_MEMORY_SCOPE_AGENT);
      while (__hip_atomic_load(c.bar, __ATOMIC_ACQUIRE, __HIP_MEMORY_SCOPE_AGENT) < (unsigned)(16 * (t + 1)))
        __builtin_amdgcn_s_sleep(2);
      __threadfence();
    }
    __syncthreads();
    if (t < TT - 1) {
      int par = (t + 1) & 1;
      for (int idx = tid; idx < 4096; idx += 256) {
        hAhi[idx] = c.hbuf_hi[par * 4096 + idx];
        hAlo[idx] = c.hbuf_lo[par * 4096 + idx];
      }
      __syncthreads();
    }
  }
}

// ---------------- dec_proj = hs @ Ws^T + Ws_b ; hws = h.ws ----------------
__global__ void k_decproj(Ctx c) {
  int tb = blockIdx.x, tid = threadIdx.x;  // block 512
  __shared__ float h[256];
  __shared__ float red[256];
  if (tid < 256) h[tid] = c.hs[tb * 256 + tid];
  __syncthreads();
  float acc = c.Ws_b[tid];
#pragma unroll 4
  for (int k = 0; k < 256; ++k) acc += h[k] * c.WsT[k * 512 + tid];
  c.dec_proj[tb * 512 + tid] = acc;
  if (tid < 256) red[tid] = h[tid] * c.ws_w[tid];
  __syncthreads();
  for (int s = 128; s > 0; s >>= 1) { if (tid < 256 && tid < s) red[tid] += red[tid + s]; __syncthreads(); }
  if (tid == 0) c.hws[tb] = red[0];
}

// ---------------- enc_proj = enc_states @ Wh^T + Wh_b ----------------
__global__ void k_encproj(Ctx c) {
  int b = blockIdx.x / 100, lt = (blockIdx.x % 100) * 4, tid = threadIdx.x; // block 512
  __shared__ float es[4][512];
  for (int i = 0; i < 4; ++i) es[i][tid] = c.enc_states[(size_t)(b * LL + lt + i) * 512 + tid];
  __syncthreads();
  float bias = c.Wh_b[tid];
  float a0 = bias, a1 = bias, a2 = bias, a3 = bias;
#pragma unroll 4
  for (int k = 0; k < 512; ++k) {
    float w = c.WhT[k * 512 + tid];
    a0 += es[0][k] * w; a1 += es[1][k] * w; a2 += es[2][k] * w; a3 += es[3][k] * w;
  }
  c.enc_proj[(size_t)(b * LL + lt + 0) * 512 + tid] = a0;
  c.enc_proj[(size_t)(b * LL + lt + 1) * 512 + tid] = a1;
  c.enc_proj[(size_t)(b * LL + lt + 2) * 512 + tid] = a2;
  c.enc_proj[(size_t)(b * LL + lt + 3) * 512 + tid] = a3;
}

// ---------------- persistent fused attention loop (partial-softmax exchange) ----------------
// 16 groups (one per b) x 16 blocks x 256 threads. Block owns l-slice [blk*25, +25).
// Per step each block publishes (m_b, sum_b, pc[512]) via relaxed agent atomics
// (sc1 -> coherent-point, no L2 invalidates). ONE relaxed-spin barrier per step;
// parity double-buffered exchange. No threadfence, no acquire spin.
__global__ void __launch_bounds__(256, 1) k_attn(Ctx c) {
  __shared__ float ep_s[25 * 512];           // 51.2 KB, resident all t
  __shared__ float wcw_s[512], wcb_s[512], vw_s[512], dp_s[512];
  __shared__ float sc_s[32];                 // own raw scores
  __shared__ float psc_s[32];                // e^{s - m_b} (0 if masked)
  __shared__ float xf_s[16];                 // e^{m_j - M} per block j
  __shared__ float ctxred[8][32];
  __shared__ float cov_s[25];
  __shared__ int idx_s[25];
  __shared__ unsigned char msk_s[32];
  __shared__ float mb_s, sb_s, M_s, S_s;
  int tid = threadIdx.x;
  int b = blockIdx.x >> 4;     // group = batch row
  int blk = blockIdx.x & 15;   // block within group
  int l0 = blk * 25;
  int wv = tid >> 6, lane = tid & 63;
  const float* epb = c.enc_proj + ((size_t)b * LL + l0) * 512;
  const float* esb = c.enc_states + ((size_t)b * LL + l0) * 512;  // own 25 rows
  for (int i = tid; i < 12800; i += 256) ep_s[i] = epb[i];
  wcw_s[tid] = c.wc_w[tid]; wcw_s[tid + 256] = c.wc_w[tid + 256];
  wcb_s[tid] = c.wc_b[tid]; wcb_s[tid + 256] = c.wc_b[tid + 256];
  vw_s[tid]  = c.v_w[tid];  vw_s[tid + 256]  = c.v_w[tid + 256];
  if (tid < 25) {
    cov_s[tid] = 0.f;
    unsigned char m = c.enc_mask[b * LL + l0 + tid];
    msk_s[tid] = m;
    idx_s[tid] = m ? 0 : (c.article_inds[b * LL + l0 + tid] - 1);
  }
  float covl_loc = 0.f;
  float vb = c.v_b[0];
  unsigned* barp = c.abar + b * 32;   // own cache line per group
  __syncthreads();
  for (int t = 0; t < TT; ++t) {
    int par = t & 1;
    // stage dec_proj row for this t
    const float* dp = c.dec_proj + (size_t)(t * 16 + b) * 512;
    dp_s[tid] = dp[tid]; dp_s[tid + 256] = dp[tid + 256];
    __syncthreads();
    // ---- phase A: raw scores for own 25 l's (all-LDS operands) ----
    for (int li = wv; li < 25; li += 4) {
      float cov = cov_s[li];
      const float* ep = ep_s + li * 512;
      float acc = 0.f;
#pragma unroll
      for (int i = 0; i < 8; ++i) {
        int j = lane + 64 * i;
        float f = ep[j] + dp_s[j] + cov * wcw_s[j] + wcb_s[j];
        acc += tanhf(f) * vw_s[j];
      }
      for (int off = 1; off < 64; off <<= 1) acc += __shfl_xor(acc, off, 64);
      if (lane == 0) sc_s[li] = acc + vb;
    }
    __syncthreads();
    // ---- local softmax partials over own 25 ----
    if (tid < 32) {
      bool ok = (tid < 25) && !msk_s[tid & 31];
      float s = ok ? sc_s[tid] : -FLT_MAX;
      float m = s;
      for (int off = 1; off < 32; off <<= 1) m = fmaxf(m, __shfl_xor(m, off, 32));
      float pv = ok ? __expf(s - m) : 0.f;
      psc_s[tid] = pv;
      float sm = pv;
      for (int off = 1; off < 32; off <<= 1) sm += __shfl_xor(sm, off, 32);
      if (tid == 0) { mb_s = m; sb_s = sm; }
    }
    __syncthreads();
    // ---- unnormalized partial context over own 25 l's (L2-resident reads) ----
    float pc0 = 0.f, pc1 = 0.f;
#pragma unroll
    for (int l = 0; l < 25; ++l) {
      float pv = psc_s[l];
      pc0 += pv * esb[(size_t)l * 512 + tid];
      pc1 += pv * esb[(size_t)l * 512 + tid + 256];
    }
    // ---- publish (coherent stores, no cache maintenance) ----
    {
      size_t xb = ((size_t)(par * 16 + b) * 16 + blk) * 512;
      cstore(&c.xpc[xb + tid], pc0);
      cstore(&c.xpc[xb + tid + 256], pc1);
      if (tid == 0) {
        cstore(&c.xm[(par * 16 + b) * 16 + blk], mb_s);
        cstore(&c.xs[(par * 16 + b) * 16 + blk], sb_s);
      }
    }
    asm volatile("s_waitcnt vmcnt(0)" ::: "memory");
    __syncthreads();
    if (tid == 0) {
      __hip_atomic_fetch_add(barp, 1u, __ATOMIC_RELAXED, __HIP_MEMORY_SCOPE_AGENT);
      while (__hip_atomic_load(barp, __ATOMIC_RELAXED, __HIP_MEMORY_SCOPE_AGENT) < 16u * (unsigned)(t + 1))
        __builtin_amdgcn_s_sleep(1);
    }
    __syncthreads();
    // ---- combine 16 partials: global M, S, per-block factors ----
    if (tid < 16) {
      float m = cload(&c.xm[(par * 16 + b) * 16 + tid]);
      float s = cload(&c.xs[(par * 16 + b) * 16 + tid]);
      float M = m;
      for (int off = 1; off < 16; off <<= 1) M = fmaxf(M, __shfl_xor(M, off, 16));
      float f = __expf(m - M);
      float z = s * f;
      for (int off = 1; off < 16; off <<= 1) z += __shfl_xor(z, off, 16);
      xf_s[tid] = f;
      if (tid == 0) { M_s = M; S_s = z; }
    }
    __syncthreads();
    float S = S_s;
    // ---- coverage + covl + mct on own l's (wave 0) ----
    if (tid < 32) {
      float cvl = 0.f, mct = 0.f;
      if (tid < 25) {
        float a = psc_s[tid] * xf_s[blk] / S;
        float nc = cov_s[tid] + a;
        cov_s[tid] = nc;
        cvl = fminf(nc, a);
        int gidx = c.gidxA[t * 16 + b];
        mct = (idx_s[tid] == gidx) ? a : 0.f;
      }
      for (int off = 1; off < 32; off <<= 1) {
        cvl += __shfl_xor(cvl, off, 32);
        mct += __shfl_xor(mct, off, 32);
      }
      if (tid == 0) {
        covl_loc += cvl;
        c.attnA[(size_t)(t * 16 + b) * 16 + blk] = mct;
      }
    }
    // ---- ctx slice: cols blk*32..+32, sum 16 partials (coherent loads) ----
    {
      int e = tid & 31, r = tid >> 5;   // r 0..7
      float part = 0.f;
#pragma unroll
      for (int jj = 0; jj < 2; ++jj) {
        int j = r + jj * 8;
        float pcv = cload(&c.xpc[((size_t)(par * 16 + b) * 16 + j) * 512 + blk * 32 + e]);
        part += pcv * xf_s[j];
      }
      ctxred[r][e] = part;
    }
    // h-part of hcbA: one block per group writes it
    if (blk == 0) {
      float hv = c.hs[(size_t)(t * 16 + b) * 256 + tid];
      c.hcbA[(size_t)t * 12288 + (tid >> 3) * 128 + b * 8 + (tid & 7)] = f2bf(hv);
    }
    __syncthreads();
    if (tid < 32) {
      float cx = 0.f;
#pragma unroll
      for (int r = 0; r < 8; ++r) cx += ctxred[r][tid];
      cx /= S;
      int jj = 256 + blk * 32 + tid;
      c.hcbA[(size_t)t * 12288 + (jj >> 3) * 128 + b * 8 + (jj & 7)] = f2bf(cx);
      float pp = cx * c.wh_w[blk * 32 + tid];
      for (int off = 1; off < 32; off <<= 1) pp += __shfl_xor(pp, off, 32);
      if (tid == 0) c.pgenA[(size_t)(t * 16 + b) * 16 + blk] = pp;
    }
    __syncthreads();  // protect LDS reuse at next t
  }
  if (tid == 0) c.covl_sum[b * 16 + blk] = covl_loc;
}

// ---------------- one-shot vocab GEMM, barrier-free, LDS-free ----------------
__global__ void __launch_bounds__(256, 4) k_vocab_all(Ctx c) {
  int tid = threadIdx.x;
  int wv = tid >> 6, lane = tid & 63;
  int n = lane & 15, q = lane >> 4;
  int cg = blockIdx.x >> 2, tg = blockIdx.x & 3;
  int nt = cg * 4 + wv;
  int col = nt * 16 + n;
  bool vld = col < VOCAB;
  int colc = vld ? col : VOCAB - 1;
  float vb = c.V_b[colc];
  int t0 = tg * 10;
  f32x4 D[10];
#pragma unroll
  for (int i = 0; i < 10; ++i) D[i] = (f32x4){0.f, 0.f, 0.f, 0.f};
  const bf16x8* A8 = (const bf16x8*)c.hcbA;
  size_t abase = ((size_t)t0 * 96) * 16 + q * 16 + n;   // + i*1536 + kc*64
  if (c.use_bf16) {
    const bf16x8* BF = (const bf16x8*)c.VF;
    size_t bbase = (size_t)nt * 1536 + q * 16 + n;      // + kc*64
    for (int kc = 0; kc < 24; ++kc) {
      bf16x8 B = BF[bbase + kc * 64];
#pragma unroll
      for (int i = 0; i < 10; ++i) {
        bf16x8 a = A8[abase + (size_t)i * 1536 + kc * 64];
        D[i] = __builtin_amdgcn_mfma_f32_16x16x32_bf16(a, B, D[i], 0, 0, 0);
      }
    }
  } else {
    for (int kc = 0; kc < 24; ++kc) {
      const float4* vr = (const float4*)(c.V_w + (size_t)colc * 768 + kc * 32 + q * 8);
      float4 b0 = vr[0], b1 = vr[1];
      bf16x8 B;
      B[0] = (short)f2bf(b0.x); B[1] = (short)f2bf(b0.y); B[2] = (short)f2bf(b0.z); B[3] = (short)f2bf(b0.w);
      B[4] = (short)f2bf(b1.x); B[5] = (short)f2bf(b1.y); B[6] = (short)f2bf(b1.z); B[7] = (short)f2bf(b1.w);
#pragma unroll
      for (int i = 0; i < 10; ++i) {
        bf16x8 a = A8[abase + (size_t)i * 1536 + kc * 64];
        D[i] = __builtin_amdgcn_mfma_f32_16x16x32_bf16(a, B, D[i], 0, 0, 0);
      }
    }
  }
#pragma unroll
  for (int i = 0; i < 10; ++i) {
    int t = t0 + i;
#pragma unroll
    for (int r = 0; r < 4; ++r) {
      int b = q * 4 + r;
      int rw = t * 16 + b;
      float lg = D[i][r] + vb;
      if (vld && col == c.gidxA[rw]) c.logitA[rw] = lg;
      float m_ = vld ? lg : -FLT_MAX;
      float s_ = vld ? 1.f : 0.f;
#pragma unroll
      for (int off = 1; off < 16; off <<= 1) {
        float om = __shfl_xor(m_, off, 16);
        float os = __shfl_xor(s_, off, 16);
        float Mm = fmaxf(m_, om);
        s_ = s_ * __expf(m_ - Mm) + os * __expf(om - Mm);
        m_ = Mm;
      }
      if (n == 0) {
        c.pairs_m[(size_t)rw * NPW + nt] = m_;
        c.pairs_s[(size_t)rw * NPW + nt] = s_;
      }
    }
  }
}

// ---------------- per-(t,b) loss from pairs ----------------
__global__ void k_final_all(Ctx c) {
  int row = blockIdx.x;  // t*16 + b
  int tid = threadIdx.x; // 256
  __shared__ float red[256];
  float m = -FLT_MAX;
  for (int i = tid; i < NPW; i += 256) m = fmaxf(m, c.pairs_m[(size_t)row * NPW + i]);
  red[tid] = m; __syncthreads();
  for (int s = 128; s > 0; s >>= 1) { if (tid < s) red[tid] = fmaxf(red[tid], red[tid + s]); __syncthreads(); }
  float M = red[0]; __syncthreads();
  float z = 0.f;
  for (int i = tid; i < NPW; i += 256)
    z += c.pairs_s[(size_t)row * NPW + i] * __expf(c.pairs_m[(size_t)row * NPW + i] - M);
  red[tid] = z; __syncthreads();
  for (int s = 128; s > 0; s >>= 1) { if (tid < s) red[tid] += red[tid + s]; __syncthreads(); }
  if (tid == 0) {
    int t = row >> 4, b = row & 15;
    int tgt = c.targets[b * TT + t];
    float lm = 0.f;
    if (tgt != 0) {
      float pgs = 0.f, ats = 0.f;
#pragma unroll
      for (int i = 0; i < 16; ++i) {
        pgs += c.pgenA[(size_t)row * 16 + i];
        ats += c.attnA[(size_t)row * 16 + i];
      }
      float pg = sigf(pgs + c.wh_b[0] + c.hws[row] + c.ws_b[0] + c.px[row] + c.wx_b[0]);
      float p = __expf(c.logitA[row] - M) / red[0];
      lm = -logf(pg * p + (1.f - pg) * ats);
    }
    c.lmA[row] = lm;
  }
}

// ---------------- output ----------------
__global__ void k_out(Ctx c) {
  int b = blockIdx.x, tid = threadIdx.x; // 64 threads
  float lm = (tid < TT) ? c.lmA[tid * 16 + b] : 0.f;
  float dl = (tid < TT && c.dec_input[b * TT + tid] > 0) ? 1.f : 0.f;
  float cv = (tid < 16) ? c.covl_sum[b * 16 + tid] : 0.f;
  for (int off = 1; off < 64; off <<= 1) {
    lm += __shfl_xor(lm, off, 64);
    dl += __shfl_xor(dl, off, 64);
    cv += __shfl_xor(cv, off, 64);
  }
  if (tid == 0) c.out[b] = lm / dl + cv / dl;
}

extern "C" void kernel_launch(void* const* d_in, const int* in_sizes, int n_in,
                              void* d_out, int out_size, void* d_ws, size_t ws_size,
                              hipStream_t stream) {
  Ctx c;
  c.enc_states = (const float*)d_in[0];
  c.enc_h      = (const float*)d_in[1];
  c.enc_c      = (const float*)d_in[2];
  c.embed      = (const float*)d_in[3];
  c.Wih        = (const float*)d_in[4];
  c.Whh        = (const float*)d_in[5];
  c.bih        = (const float*)d_in[6];
  c.bhh        = (const float*)d_in[7];
  c.Wh_w       = (const float*)d_in[8];
  c.Wh_b       = (const float*)d_in[9];
  c.Ws_w       = (const float*)d_in[10];
  c.Ws_b       = (const float*)d_in[11];
  c.wc_w       = (const float*)d_in[12];
  c.wc_b       = (const float*)d_in[13];
  c.v_w        = (const float*)d_in[14];
  c.v_b        = (const float*)d_in[15];
  c.wh_w       = (const float*)d_in[16];
  c.wh_b       = (const float*)d_in[17];
  c.ws_w       = (const float*)d_in[18];
  c.ws_b       = (const float*)d_in[19];
  c.wx_w       = (const float*)d_in[20];
  c.wx_b       = (const float*)d_in[21];
  c.V_w        = (const float*)d_in[22];
  c.V_b        = (const float*)d_in[23];
  c.dec_input  = (const int*)d_in[24];
  c.targets    = (const int*)d_in[25];
  c.article_inds = (const int*)d_in[26];
  c.enc_mask   = (const unsigned char*)d_in[27];

  float* p = (float*)d_ws;
  c.Gx = p;        p += TT * BB * 1024;
  c.hs = p;        p += TT * BB * 256;
  c.dec_proj = p;  p += TT * BB * 512;
  c.enc_proj = p;  p += (size_t)BB * LL * 512;
  c.WihT = p;      p += 1024 * 256;
  c.WsT = p;       p += 512 * 256;
  c.WhT = p;       p += 512 * 512;
  c.coverage = p;  p += BB * LL;
  c.scores = p;    p += 2 * BB * LL;
  c.hcbA = (unsigned short*)p; p += TT * BB * 768 / 2;
  c.pairs_m = p;   p += (size_t)640 * NPW;
  c.pairs_s = p;   p += (size_t)640 * NPW;
  c.px = p;        p += TT * BB;
  c.hws = p;       p += TT * BB;
  c.pgenA = p;     p += 640 * 16;
  c.attnA = p;     p += 640 * 16;
  c.logitA = p;    p += 640;
  c.lmA = p;       p += 640;
  c.gidxA = (int*)p; p += 640;
  c.covl_sum = p;  p += 256;
  c.hbuf_hi = (unsigned short*)p; p += 2 * 4096 / 2;
  c.hbuf_lo = (unsigned short*)p; p += 2 * 4096 / 2;
  c.bar = (unsigned*)p; p += 16;
  c.abar = (unsigned*)p; p += 512;   // 16 groups * 32-uint stride
  c.xm = p;        p += 2 * 16 * 16;
  c.xs = p;        p += 2 * 16 * 16;
  c.xpc = p;       p += (size_t)2 * 16 * 16 * 512;
  c.VF = (unsigned short*)p;
  size_t used_bytes = (size_t)((char*)p - (char*)d_ws);
  size_t vf_bytes = (size_t)NTILES * 12288 * 2;
  c.use_bf16 = (used_bytes + vf_bytes <= ws_size) ? 1 : 0;
  c.out = (float*)d_out;

  k_init<<<3, 256, 0, stream>>>(c);
  if (c.use_bf16) k_cvtF<<<NTILES, 256, 0, stream>>>(c.V_w, c.VF);
  k_transpose<<<dim3(8, 32), dim3(32, 8), 0, stream>>>(c.Wih, c.WihT, 1024, 256);
  k_transpose<<<dim3(8, 16), dim3(32, 8), 0, stream>>>(c.Ws_w, c.WsT, 512, 256);
  k_transpose<<<dim3(16, 16), dim3(32, 8), 0, stream>>>(c.Wh_w, c.WhT, 512, 512);
  k_gx<<<TT * BB, 256, 0, stream>>>(c);
  k_encproj<<<16 * 100, 512, 0, stream>>>(c);
  k_lstm<<<16, 256, 0, stream>>>(c);
  k_decproj<<<TT * BB, 512, 0, stream>>>(c);
  k_attn<<<256, 256, 0, stream>>>(c);
  k_vocab_all<<<782 * 4, 256, 0, stream>>>(c);
  k_final_all<<<640, 256, 0, stream>>>(c);
  k_out<<<16, 64, 0, stream>>>(c);
}

// Round 4
// 1329.405 us; speedup vs baseline: 1.7452x; 1.0609x over previous
//
#include <hip/hip_runtime.h>
#include <float.h>
#include <math.h>

// Problem constants
#define BB 16
#define LL 400
#define TT 40
#define HH 256
#define EE 256
#define VOCAB 50000
#define NTILES 3128   // vocab tiles of 16 cols, 3128*16 = 50048 >= 50000
#define NPW NTILES    // pairs width

typedef __attribute__((ext_vector_type(8))) short bf16x8;
typedef __attribute__((ext_vector_type(4))) float f32x4;
typedef __attribute__((ext_vector_type(8))) unsigned short ushort8;

struct Ctx {
  // inputs
  const float *enc_states, *enc_h, *enc_c, *embed;
  const float *Wih, *Whh, *bih, *bhh;
  const float *Wh_w, *Wh_b, *Ws_w, *Ws_b;
  const float *wc_w, *wc_b, *v_w, *v_b;
  const float *wh_w, *wh_b, *ws_w, *ws_b, *wx_w, *wx_b;
  const float *V_w, *V_b;
  const int *dec_input, *targets, *article_inds;
  const unsigned char *enc_mask;
  // workspace
  float *Gx;        // [T,B,1024]
  float *hs;        // [T,B,256]
  float *dec_proj;  // [T,B,512]
  float *enc_proj;  // [B,L,512]
  float *WihT, *WsT, *WhT;
  float *coverage;  // unused (layout stability)
  float *scores;    // unused (layout stability)
  unsigned short *hcbA; // [T][96][16][8] bf16 A-fragments of concat(h,ctx)
  float *pairs_m, *pairs_s;  // [640][NPW]
  float *px, *hws;  // [T*B]
  float *pgenA, *attnA;      // [640][16] partials
  float *logitA, *lmA;       // [640]
  int *gidxA;       // [640]
  float *covl_sum;  // [16][16] partials
  unsigned short *hbuf_hi, *hbuf_lo;  // [2][4096] LSTM h exchange
  unsigned *bar;    // LSTM barrier
  unsigned *abar;   // attention flags: [16 groups][16 blocks] monotonic step counters
  float *xm, *xs;   // (xms overlays these) [2][16][16] packed (m,s) as u64
  float *xpc;       // [2][16][16][512] per-block unnormalized partial context
  unsigned long long *xms;
  unsigned short *VF;  // [NTILES][24][4][16][8] bf16 V_w in B-frag order (optional)
  int use_bf16;
  float *out;       // [B]
};

__device__ __forceinline__ float sigf(float x) { return 1.f / (1.f + expf(-x)); }

// fast tanh: ~5 VALU ops via v_exp; saturates correctly
__device__ __forceinline__ float tanhfast(float x) {
  float ax = fabsf(x);
  float e = __expf(2.f * ax);
  float r = 1.f - 2.f / (e + 1.f);
  return copysignf(r, x);
}

__device__ __forceinline__ unsigned short f2bf(float x) {
  unsigned u = __builtin_bit_cast(unsigned, x);
  u = (u + 0x7FFFu + ((u >> 16) & 1u)) >> 16;
  return (unsigned short)u;
}
__device__ __forceinline__ float bf2f(unsigned short h) {
  unsigned u = ((unsigned)h) << 16;
  return __builtin_bit_cast(float, u);
}

// coherent (sc1) helpers: relaxed agent-scope atomics -> serviced at the
// device coherent point, no cache-maintenance ops, no L2 pollution.
__device__ __forceinline__ void cstore(float* p, float v) {
  __hip_atomic_store(p, v, __ATOMIC_RELAXED, __HIP_MEMORY_SCOPE_AGENT);
}
__device__ __forceinline__ float cload(const float* p) {
  return __hip_atomic_load(p, __ATOMIC_RELAXED, __HIP_MEMORY_SCOPE_AGENT);
}
__device__ __forceinline__ void cstoreu(unsigned* p, unsigned v) {
  __hip_atomic_store(p, v, __ATOMIC_RELAXED, __HIP_MEMORY_SCOPE_AGENT);
}
__device__ __forceinline__ unsigned cloadu(const unsigned* p) {
  return __hip_atomic_load(p, __ATOMIC_RELAXED, __HIP_MEMORY_SCOPE_AGENT);
}
__device__ __forceinline__ void cstore64(unsigned long long* p, unsigned long long v) {
  __hip_atomic_store(p, v, __ATOMIC_RELAXED, __HIP_MEMORY_SCOPE_AGENT);
}
__device__ __forceinline__ unsigned long long cload64(const unsigned long long* p) {
  return __hip_atomic_load(p, __ATOMIC_RELAXED, __HIP_MEMORY_SCOPE_AGENT);
}

// ---------------- init ----------------
__global__ void k_init(Ctx c) {
  int i = blockIdx.x * 256 + threadIdx.x;
  if (i == 0) *c.bar = 0u;
  if (i < 512) c.abar[i] = 0u;
  if (i < 640) {
    int t = i >> 4, b = i & 15;
    int tgt = c.targets[b * TT + t];
    c.gidxA[i] = (tgt != 0) ? tgt - 1 : 0;
  }
}

// ---------------- V_w fp32 -> bf16 in MFMA B-frag order ----------------
__global__ void __launch_bounds__(256) k_cvtF(const float* __restrict__ V, unsigned short* __restrict__ VF) {
  __shared__ unsigned short tile[16][800];
  int nt = blockIdx.x;
  int tid = threadIdx.x;
  for (int u = tid; u < 3072; u += 256) {
    int rr = u / 192, cc = u % 192;
    int v = nt * 16 + rr;
    float4 x = {0.f, 0.f, 0.f, 0.f};
    if (v < VOCAB) x = ((const float4*)(V + (size_t)v * 768))[cc];
    unsigned short* d = &tile[rr][cc * 4];
    d[0] = f2bf(x.x); d[1] = f2bf(x.y); d[2] = f2bf(x.z); d[3] = f2bf(x.w);
  }
  __syncthreads();
  ushort8* dst = (ushort8*)(VF + (size_t)nt * 12288);
  for (int u = tid; u < 1536; u += 256) {
    int n = u & 15, kq = u >> 4;
    const unsigned short* s = &tile[n][kq * 8];
    ushort8 o;
#pragma unroll
    for (int j = 0; j < 8; ++j) o[j] = s[j];
    dst[u] = o;
  }
}

// ---------------- tiled transpose ----------------
__global__ void k_transpose(const float* __restrict__ in, float* __restrict__ out, int R, int C) {
  __shared__ float tile[32][33];
  int bx = blockIdx.x * 32, by = blockIdx.y * 32;
  int tx = threadIdx.x, ty = threadIdx.y;
  for (int i = ty; i < 32; i += 8) tile[i][tx] = in[(by + i) * C + bx + tx];
  __syncthreads();
  for (int i = ty; i < 32; i += 8) out[(bx + i) * R + by + tx] = tile[tx][i];
}

#define FMA4(acc, s, ww) { (acc).x += (s)*(ww).x; (acc).y += (s)*(ww).y; (acc).z += (s)*(ww).z; (acc).w += (s)*(ww).w; }

// ---------------- Gx: 8 batch rows per weight pass ----------------
// grid 80 = 40 t * 2 halves; 256 thr; each thread owns 4 output cols (float4)
__global__ void __launch_bounds__(256) k_gx(Ctx c) {
  int t = blockIdx.x >> 1, hh = blockIdx.x & 1;
  int tid = threadIdx.x;
  __shared__ int tok_s[8];
  __shared__ float x[8][256];
  if (tid < 8) tok_s[tid] = c.dec_input[(hh * 8 + tid) * TT + t];
  __syncthreads();
  for (int u = tid; u < 2048; u += 256) {
    int r = u >> 8, k = u & 255;
    x[r][k] = c.embed[(size_t)tok_s[r] * 256 + k];
  }
  __syncthreads();
  const float4* WT4 = (const float4*)c.WihT;
  float4 bias = ((const float4*)c.bih)[tid];
  float4 b2 = ((const float4*)c.bhh)[tid];
  bias.x += b2.x; bias.y += b2.y; bias.z += b2.z; bias.w += b2.w;
  float4 acc[8];
#pragma unroll
  for (int r = 0; r < 8; ++r) acc[r] = bias;
  for (int k = 0; k < 256; k += 4) {
    float4 w0 = WT4[(k + 0) * 256 + tid];
    float4 w1 = WT4[(k + 1) * 256 + tid];
    float4 w2 = WT4[(k + 2) * 256 + tid];
    float4 w3 = WT4[(k + 3) * 256 + tid];
#pragma unroll
    for (int r = 0; r < 8; ++r) {
      float4 e4 = *(const float4*)&x[r][k];
      FMA4(acc[r], e4.x, w0); FMA4(acc[r], e4.y, w1);
      FMA4(acc[r], e4.z, w2); FMA4(acc[r], e4.w, w3);
    }
  }
#pragma unroll
  for (int r = 0; r < 8; ++r)
    ((float4*)c.Gx)[(size_t)(t * 16 + hh * 8 + r) * 256 + tid] = acc[r];
  // px: row r = tid>>5 (8 rows), 32 lanes each
  {
    int r = tid >> 5, l32 = tid & 31;
    float p = 0.f;
#pragma unroll
    for (int i = 0; i < 8; ++i) {
      int k = l32 + 32 * i;
      p += x[r][k] * c.wx_w[k];
    }
    for (int off = 1; off < 32; off <<= 1) p += __shfl_xor(p, off, 32);
    if (l32 == 0) c.px[t * 16 + hh * 8 + r] = p;
  }
}

// ---------------- persistent MFMA LSTM (unchanged, proven) ----------------
__global__ void __launch_bounds__(256) k_lstm(Ctx c) {
  __shared__ unsigned short hAhi[4096], hAlo[4096];
  __shared__ float gs[4][16][16];
  int w = blockIdx.x, tid = threadIdx.x;
  int g = tid >> 6, lane = tid & 63;
  int n = lane & 15, q = lane >> 4;
  bf16x8 Bhi[8], Blo[8];
  {
    const float* wr = c.Whh + (size_t)(g * 256 + w * 16 + n) * 256;
#pragma unroll
    for (int kc = 0; kc < 8; ++kc) {
      const float* p8 = wr + kc * 32 + q * 8;
#pragma unroll
      for (int j = 0; j < 8; ++j) {
        float x = p8[j];
        unsigned short hi = f2bf(x);
        unsigned short lo = f2bf(x - bf2f(hi));
        Bhi[kc][j] = (short)hi; Blo[kc][j] = (short)lo;
      }
    }
  }
  for (int idx = tid; idx < 4096; idx += 256) {
    int b = idx >> 8, k = idx & 255;
    float x = c.enc_h[idx];
    unsigned short hi = f2bf(x);
    unsigned short lo = f2bf(x - bf2f(hi));
    int pos = (((k >> 5) * 4 + ((k >> 3) & 3)) * 16 + b) * 8 + (k & 7);
    hAhi[pos] = hi; hAlo[pos] = lo;
  }
  int bu = tid >> 4, ju = tid & 15;
  float creg = c.enc_c[bu * 256 + w * 16 + ju];
  __syncthreads();
  const bf16x8* Ahi = (const bf16x8*)hAhi;
  const bf16x8* Alo = (const bf16x8*)hAlo;
  int col = g * 256 + w * 16 + n;
  for (int t = 0; t < TT; ++t) {
    const float* gxp = c.Gx + (size_t)(t * 16) * 1024 + col;
    f32x4 acc;
    acc[0] = gxp[(q * 4 + 0) * 1024]; acc[1] = gxp[(q * 4 + 1) * 1024];
    acc[2] = gxp[(q * 4 + 2) * 1024]; acc[3] = gxp[(q * 4 + 3) * 1024];
#pragma unroll
    for (int kc = 0; kc < 8; ++kc) {
      bf16x8 ah = Ahi[(kc * 4 + q) * 16 + n];
      bf16x8 al = Alo[(kc * 4 + q) * 16 + n];
      acc = __builtin_amdgcn_mfma_f32_16x16x32_bf16(ah, Bhi[kc], acc, 0, 0, 0);
      acc = __builtin_amdgcn_mfma_f32_16x16x32_bf16(al, Bhi[kc], acc, 0, 0, 0);
      acc = __builtin_amdgcn_mfma_f32_16x16x32_bf16(ah, Blo[kc], acc, 0, 0, 0);
    }
#pragma unroll
    for (int r = 0; r < 4; ++r) gs[g][q * 4 + r][n] = acc[r];
    __syncthreads();
    {
      float ig = gs[0][bu][ju], fg = gs[1][bu][ju], gg = gs[2][bu][ju], og = gs[3][bu][ju];
      creg = sigf(fg) * creg + sigf(ig) * tanhf(gg);
      float hv = sigf(og) * tanhf(creg);
      int j = w * 16 + ju;
      c.hs[(t * 16 + bu) * 256 + j] = hv;
      unsigned short hi = f2bf(hv);
      unsigned short lo = f2bf(hv - bf2f(hi));
      int pos = (((j >> 5) * 4 + ((j >> 3) & 3)) * 16 + bu) * 8 + (j & 7);
      int par = (t + 1) & 1;
      c.hbuf_hi[par * 4096 + pos] = hi;
      c.hbuf_lo[par * 4096 + pos] = lo;
    }
    __threadfence();
    __syncthreads();
    if (tid == 0) {
      __hip_atomic_fetch_add(c.bar, 1u, __ATOMIC_ACQ_REL, __HIP_MEMORY_SCOPE_AGENT);
      while (__hip_atomic_load(c.bar, __ATOMIC_ACQUIRE, __HIP_MEMORY_SCOPE_AGENT) < (unsigned)(16 * (t + 1)))
        __builtin_amdgcn_s_sleep(2);
      __threadfence();
    }
    __syncthreads();
    if (t < TT - 1) {
      int par = (t + 1) & 1;
      for (int idx = tid; idx < 4096; idx += 256) {
        hAhi[idx] = c.hbuf_hi[par * 4096 + idx];
        hAlo[idx] = c.hbuf_lo[par * 4096 + idx];
      }
      __syncthreads();
    }
  }
}

// ---------------- dec_proj: 8 rows per weight pass ----------------
// grid 80 = 40 t * 2 halves; 512 thr, each thread 1 col
__global__ void __launch_bounds__(512) k_decproj(Ctx c) {
  int t = blockIdx.x >> 1, hh = blockIdx.x & 1;
  int tid = threadIdx.x;
  __shared__ float h[8][256];
  for (int u = tid; u < 2048; u += 512)
    h[u >> 8][u & 255] = c.hs[(size_t)(t * 16 + hh * 8 + (u >> 8)) * 256 + (u & 255)];
  __syncthreads();
  float bias = c.Ws_b[tid];
  float acc[8];
#pragma unroll
  for (int r = 0; r < 8; ++r) acc[r] = bias;
  for (int k = 0; k < 256; k += 4) {
    float w0 = c.WsT[(k + 0) * 512 + tid];
    float w1 = c.WsT[(k + 1) * 512 + tid];
    float w2 = c.WsT[(k + 2) * 512 + tid];
    float w3 = c.WsT[(k + 3) * 512 + tid];
#pragma unroll
    for (int r = 0; r < 8; ++r) {
      float4 e4 = *(const float4*)&h[r][k];
      acc[r] += e4.x * w0 + e4.y * w1 + e4.z * w2 + e4.w * w3;
    }
  }
#pragma unroll
  for (int r = 0; r < 8; ++r)
    c.dec_proj[(size_t)(t * 16 + hh * 8 + r) * 512 + tid] = acc[r];
  // hws: wave wv handles row wv (8 waves)
  {
    int wv = tid >> 6, lane = tid & 63;
    float p = 0.f;
#pragma unroll
    for (int i = 0; i < 4; ++i) {
      int k = lane + 64 * i;
      p += h[wv][k] * c.ws_w[k];
    }
    for (int off = 1; off < 64; off <<= 1) p += __shfl_xor(p, off, 64);
    if (lane == 0) c.hws[t * 16 + hh * 8 + wv] = p;
  }
}

// ---------------- enc_proj: 16 rows per weight pass ----------------
// grid 400 = 16 b * 25 l-tiles; 512 thr, each thread 1 col
__global__ void __launch_bounds__(512) k_encproj(Ctx c) {
  int b = blockIdx.x / 25, lt = (blockIdx.x % 25) * 16;
  int tid = threadIdx.x;
  __shared__ float es[16][512];
  for (int u = tid; u < 8192; u += 512)
    es[u >> 9][u & 511] = c.enc_states[(size_t)(b * LL + lt) * 512 + u];
  __syncthreads();
  float bias = c.Wh_b[tid];
  float acc[16];
#pragma unroll
  for (int r = 0; r < 16; ++r) acc[r] = bias;
  for (int k = 0; k < 512; k += 4) {
    float w0 = c.WhT[(k + 0) * 512 + tid];
    float w1 = c.WhT[(k + 1) * 512 + tid];
    float w2 = c.WhT[(k + 2) * 512 + tid];
    float w3 = c.WhT[(k + 3) * 512 + tid];
#pragma unroll
    for (int r = 0; r < 16; ++r) {
      float4 e4 = *(const float4*)&es[r][k];
      acc[r] += e4.x * w0 + e4.y * w1 + e4.z * w2 + e4.w * w3;
    }
  }
#pragma unroll
  for (int r = 0; r < 16; ++r)
    c.enc_proj[(size_t)(b * LL + lt + r) * 512 + tid] = acc[r];
}

// ---------------- persistent fused attention loop ----------------
// 16 groups (per b) x 16 blocks x 512 thr. Block owns l-slice [blk*25, +25).
// Exchange via sc1 relaxed atomics; flag-store + parallel-poll barrier;
// single fabric round-trip after barrier (pc loads issued before M/S combine).
__global__ void __launch_bounds__(512, 2) k_attn(Ctx c) {
  __shared__ float ep_s[25 * 512];           // 51.2 KB, resident all t
  __shared__ float wcw_s[512], wcb_s[512], vw_s[512], dp_s[512];
  __shared__ float sc_s[32];                 // own raw scores
  __shared__ float psc_s[32];                // e^{s - m_b} (0 if masked)
  __shared__ float xf_s[16];                 // e^{m_j - M}
  __shared__ float ctxred[16][32];
  __shared__ float cov_s[25];
  __shared__ int idx_s[25];
  __shared__ unsigned char msk_s[32];
  __shared__ float mb_s, sb_s, S_s;
  int tid = threadIdx.x;
  int b = blockIdx.x >> 4;
  int blk = blockIdx.x & 15;
  int l0 = blk * 25;
  int wv = tid >> 6, lane = tid & 63;
  const float* epb = c.enc_proj + ((size_t)b * LL + l0) * 512;
  const float* esb = c.enc_states + ((size_t)b * LL + l0) * 512;
  for (int i = tid; i < 12800; i += 512) ep_s[i] = epb[i];
  wcw_s[tid] = c.wc_w[tid];
  wcb_s[tid] = c.wc_b[tid];
  vw_s[tid]  = c.v_w[tid];
  if (tid < 25) {
    cov_s[tid] = 0.f;
    unsigned char m = c.enc_mask[b * LL + l0 + tid];
    msk_s[tid] = m;
    idx_s[tid] = m ? 0 : (c.article_inds[b * LL + l0 + tid] - 1);
  }
  float covl_loc = 0.f;
  float vb = c.v_b[0];
  float dpr = c.dec_proj[(size_t)(0 * 16 + b) * 512 + tid];  // prefetch t=0
  __syncthreads();
  for (int t = 0; t < TT; ++t) {
    int par = t & 1;
    dp_s[tid] = dpr;
    __syncthreads();
    // ---- phase A: 4 rows per wave, interleaved chains ----
    {
      int r0 = wv, r1 = wv + 8, r2 = wv + 16;
      bool v3 = (wv == 0);
      float c0 = cov_s[r0], c1 = cov_s[r1], c2 = cov_s[r2], c3 = cov_s[24];
      const float *e0 = ep_s + r0 * 512, *e1 = ep_s + r1 * 512;
      const float *e2 = ep_s + r2 * 512, *e3 = ep_s + 24 * 512;
      float a0 = 0.f, a1 = 0.f, a2 = 0.f, a3 = 0.f;
#pragma unroll
      for (int i = 0; i < 8; ++i) {
        int j = lane + 64 * i;
        float base = dp_s[j] + wcb_s[j];
        float ww = wcw_s[j], vv = vw_s[j];
        a0 += tanhfast(e0[j] + base + c0 * ww) * vv;
        a1 += tanhfast(e1[j] + base + c1 * ww) * vv;
        a2 += tanhfast(e2[j] + base + c2 * ww) * vv;
        if (v3) a3 += tanhfast(e3[j] + base + c3 * ww) * vv;
      }
#pragma unroll
      for (int off = 1; off < 64; off <<= 1) {
        a0 += __shfl_xor(a0, off, 64);
        a1 += __shfl_xor(a1, off, 64);
        a2 += __shfl_xor(a2, off, 64);
        a3 += __shfl_xor(a3, off, 64);
      }
      if (lane == 0) {
        sc_s[r0] = a0 + vb; sc_s[r1] = a1 + vb; sc_s[r2] = a2 + vb;
        if (v3) sc_s[24] = a3 + vb;
      }
    }
    __syncthreads();
    // ---- local softmax partials over own 25 ----
    if (tid < 32) {
      bool ok = (tid < 25) && !msk_s[tid & 31];
      float s = ok ? sc_s[tid] : -FLT_MAX;
      float m = s;
      for (int off = 1; off < 32; off <<= 1) m = fmaxf(m, __shfl_xor(m, off, 32));
      float pv = ok ? __expf(s - m) : 0.f;
      psc_s[tid] = pv;
      float sm = pv;
      for (int off = 1; off < 32; off <<= 1) sm += __shfl_xor(sm, off, 32);
      if (tid == 0) { mb_s = m; sb_s = sm; }
    }
    __syncthreads();
    // ---- partial context over own 25 l's (1 col/thread, L2 reads) ----
    float pc = 0.f;
#pragma unroll
    for (int l = 0; l < 25; ++l) pc += psc_s[l] * esb[(size_t)l * 512 + tid];
    // ---- publish ----
    {
      size_t xb = ((size_t)(par * 16 + b) * 16 + blk) * 512;
      cstore(&c.xpc[xb + tid], pc);
      if (tid == 0) {
        unsigned long long pk = ((unsigned long long)__builtin_bit_cast(unsigned, sb_s) << 32)
                              | __builtin_bit_cast(unsigned, mb_s);
        cstore64(&c.xms[(par * 16 + b) * 16 + blk], pk);
      }
    }
    asm volatile("s_waitcnt vmcnt(0)" ::: "memory");
    // overlap under barrier: archive h, prefetch next dec_proj
    if (blk == 0 && tid < 256) {
      float hv = c.hs[(size_t)(t * 16 + b) * 256 + tid];
      c.hcbA[(size_t)t * 12288 + (tid >> 3) * 128 + b * 8 + (tid & 7)] = f2bf(hv);
    }
    {
      int tn = (t + 1 < TT) ? t + 1 : t;
      dpr = c.dec_proj[(size_t)(tn * 16 + b) * 512 + tid];
    }
    __syncthreads();
    // ---- flag-store + parallel-poll group barrier ----
    if (tid == 0) cstoreu(&c.abar[b * 16 + blk], (unsigned)(t + 1));
    if (tid < 16) {
      while (cloadu(&c.abar[b * 16 + tid]) < (unsigned)(t + 1))
        __builtin_amdgcn_s_sleep(1);
    }
    __syncthreads();
    // ---- single fabric RT: issue pc loads, combine M/S in parallel ----
    float pcv = cload(&c.xpc[((size_t)(par * 16 + b) * 16 + (tid >> 5)) * 512 + blk * 32 + (tid & 31)]);
    if (tid < 16) {
      unsigned long long pk = cload64(&c.xms[(par * 16 + b) * 16 + tid]);
      float m = __builtin_bit_cast(float, (unsigned)(pk & 0xFFFFFFFFu));
      float s = __builtin_bit_cast(float, (unsigned)(pk >> 32));
      float M = m;
      for (int off = 1; off < 16; off <<= 1) M = fmaxf(M, __shfl_xor(M, off, 16));
      float f = __expf(m - M);
      float z = s * f;
      for (int off = 1; off < 16; off <<= 1) z += __shfl_xor(z, off, 16);
      xf_s[tid] = f;
      if (tid == 0) S_s = z;
    }
    __syncthreads();
    ctxred[tid >> 5][tid & 31] = pcv * xf_s[tid >> 5];
    // coverage + covl + mct on own l's
    if (tid < 32) {
      float cvl = 0.f, mct = 0.f;
      if (tid < 25) {
        float a = psc_s[tid] * xf_s[blk] / S_s;
        float nc = cov_s[tid] + a;
        cov_s[tid] = nc;
        cvl = fminf(nc, a);
        int gidx = c.gidxA[t * 16 + b];
        mct = (idx_s[tid] == gidx) ? a : 0.f;
      }
      for (int off = 1; off < 32; off <<= 1) {
        cvl += __shfl_xor(cvl, off, 32);
        mct += __shfl_xor(mct, off, 32);
      }
      if (tid == 0) {
        covl_loc += cvl;
        c.attnA[(size_t)(t * 16 + b) * 16 + blk] = mct;
      }
    }
    __syncthreads();
    if (tid < 32) {
      float cx = 0.f;
#pragma unroll
      for (int r = 0; r < 16; ++r) cx += ctxred[r][tid];
      cx /= S_s;
      int jj = 256 + blk * 32 + tid;
      c.hcbA[(size_t)t * 12288 + (jj >> 3) * 128 + b * 8 + (jj & 7)] = f2bf(cx);
      float pp = cx * c.wh_w[blk * 32 + tid];
      for (int off = 1; off < 32; off <<= 1) pp += __shfl_xor(pp, off, 32);
      if (tid == 0) c.pgenA[(size_t)(t * 16 + b) * 16 + blk] = pp;
    }
    __syncthreads();  // protect LDS reuse at next t
  }
  if (tid == 0) c.covl_sum[b * 16 + blk] = covl_loc;
}

// ---------------- one-shot vocab GEMM: 20 t per block, 2-deep B prefetch ----------------
// grid 1568 = 98*16; cg = (bid>>4)*8 + (bid&7) so the 2 t-groups sharing a
// VF tile land on the same XCD (same bid%8) adjacently.
__global__ void __launch_bounds__(256, 2) k_vocab_all(Ctx c) {
  int tid = threadIdx.x;
  int wv = tid >> 6, lane = tid & 63;
  int n = lane & 15, q = lane >> 4;
  int bid = blockIdx.x;
  int cg = (bid >> 4) * 8 + (bid & 7);   // 0..783
  int tg = (bid >> 3) & 1;
  int nt = cg * 4 + wv;
  int ntc = (nt < NTILES) ? nt : NTILES - 1;
  int col = nt * 16 + n;
  bool vld = (nt < NTILES) && (col < VOCAB);
  int colc = (col < VOCAB) ? col : VOCAB - 1;
  float vb = c.V_b[colc];
  int t0 = tg * 20;
  f32x4 D[20];
#pragma unroll
  for (int i = 0; i < 20; ++i) D[i] = (f32x4){0.f, 0.f, 0.f, 0.f};
  const bf16x8* A8 = (const bf16x8*)c.hcbA;
  size_t abase = ((size_t)t0 * 96) * 16 + q * 16 + n;   // + i*1536 + kc*64
  if (c.use_bf16) {
    const bf16x8* BF = (const bf16x8*)c.VF;
    size_t bbase = (size_t)ntc * 1536 + q * 16 + n;
    bf16x8 B0 = BF[bbase], B1 = BF[bbase + 64];
    for (int kc = 0; kc < 24; ++kc) {
      bf16x8 Bn = (kc < 22) ? BF[bbase + (size_t)(kc + 2) * 64] : B0;
#pragma unroll
      for (int i = 0; i < 20; ++i) {
        bf16x8 a = A8[abase + (size_t)i * 1536 + kc * 64];
        D[i] = __builtin_amdgcn_mfma_f32_16x16x32_bf16(a, B0, D[i], 0, 0, 0);
      }
      B0 = B1; B1 = Bn;
    }
  } else {
    for (int kc = 0; kc < 24; ++kc) {
      const float4* vr = (const float4*)(c.V_w + (size_t)colc * 768 + kc * 32 + q * 8);
      float4 b0 = vr[0], b1 = vr[1];
      bf16x8 B;
      B[0] = (short)f2bf(b0.x); B[1] = (short)f2bf(b0.y); B[2] = (short)f2bf(b0.z); B[3] = (short)f2bf(b0.w);
      B[4] = (short)f2bf(b1.x); B[5] = (short)f2bf(b1.y); B[6] = (short)f2bf(b1.z); B[7] = (short)f2bf(b1.w);
#pragma unroll
      for (int i = 0; i < 20; ++i) {
        bf16x8 a = A8[abase + (size_t)i * 1536 + kc * 64];
        D[i] = __builtin_amdgcn_mfma_f32_16x16x32_bf16(a, B, D[i], 0, 0, 0);
      }
    }
  }
#pragma unroll
  for (int i = 0; i < 20; ++i) {
    int t = t0 + i;
#pragma unroll
    for (int r = 0; r < 4; ++r) {
      int b = q * 4 + r;
      int rw = t * 16 + b;
      float lg = D[i][r] + vb;
      if (vld && col == c.gidxA[rw]) c.logitA[rw] = lg;
      float m_ = vld ? lg : -FLT_MAX;
      float s_ = vld ? 1.f : 0.f;
#pragma unroll
      for (int off = 1; off < 16; off <<= 1) {
        float om = __shfl_xor(m_, off, 16);
        float os = __shfl_xor(s_, off, 16);
        float Mm = fmaxf(m_, om);
        s_ = s_ * __expf(m_ - Mm) + os * __expf(om - Mm);
        m_ = Mm;
      }
      if (n == 0 && nt < NTILES) {
        c.pairs_m[(size_t)rw * NPW + nt] = m_;
        c.pairs_s[(size_t)rw * NPW + nt] = s_;
      }
    }
  }
}

// ---------------- per-(t,b) loss from pairs ----------------
__global__ void k_final_all(Ctx c) {
  int row = blockIdx.x;
  int tid = threadIdx.x;
  __shared__ float red[256];
  float m = -FLT_MAX;
  for (int i = tid; i < NPW; i += 256) m = fmaxf(m, c.pairs_m[(size_t)row * NPW + i]);
  red[tid] = m; __syncthreads();
  for (int s = 128; s > 0; s >>= 1) { if (tid < s) red[tid] = fmaxf(red[tid], red[tid + s]); __syncthreads(); }
  float M = red[0]; __syncthreads();
  float z = 0.f;
  for (int i = tid; i < NPW; i += 256)
    z += c.pairs_s[(size_t)row * NPW + i] * __expf(c.pairs_m[(size_t)row * NPW + i] - M);
  red[tid] = z; __syncthreads();
  for (int s = 128; s > 0; s >>= 1) { if (tid < s) red[tid] += red[tid + s]; __syncthreads(); }
  if (tid == 0) {
    int t = row >> 4, b = row & 15;
    int tgt = c.targets[b * TT + t];
    float lm = 0.f;
    if (tgt != 0) {
      float pgs = 0.f, ats = 0.f;
#pragma unroll
      for (int i = 0; i < 16; ++i) {
        pgs += c.pgenA[(size_t)row * 16 + i];
        ats += c.attnA[(size_t)row * 16 + i];
      }
      float pg = sigf(pgs + c.wh_b[0] + c.hws[row] + c.ws_b[0] + c.px[row] + c.wx_b[0]);
      float p = __expf(c.logitA[row] - M) / red[0];
      lm = -logf(pg * p + (1.f - pg) * ats);
    }
    c.lmA[row] = lm;
  }
}

// ---------------- output ----------------
__global__ void k_out(Ctx c) {
  int b = blockIdx.x, tid = threadIdx.x;
  float lm = (tid < TT) ? c.lmA[tid * 16 + b] : 0.f;
  float dl = (tid < TT && c.dec_input[b * TT + tid] > 0) ? 1.f : 0.f;
  float cv = (tid < 16) ? c.covl_sum[b * 16 + tid] : 0.f;
  for (int off = 1; off < 64; off <<= 1) {
    lm += __shfl_xor(lm, off, 64);
    dl += __shfl_xor(dl, off, 64);
    cv += __shfl_xor(cv, off, 64);
  }
  if (tid == 0) c.out[b] = lm / dl + cv / dl;
}

extern "C" void kernel_launch(void* const* d_in, const int* in_sizes, int n_in,
                              void* d_out, int out_size, void* d_ws, size_t ws_size,
                              hipStream_t stream) {
  Ctx c;
  c.enc_states = (const float*)d_in[0];
  c.enc_h      = (const float*)d_in[1];
  c.enc_c      = (const float*)d_in[2];
  c.embed      = (const float*)d_in[3];
  c.Wih        = (const float*)d_in[4];
  c.Whh        = (const float*)d_in[5];
  c.bih        = (const float*)d_in[6];
  c.bhh        = (const float*)d_in[7];
  c.Wh_w       = (const float*)d_in[8];
  c.Wh_b       = (const float*)d_in[9];
  c.Ws_w       = (const float*)d_in[10];
  c.Ws_b       = (const float*)d_in[11];
  c.wc_w       = (const float*)d_in[12];
  c.wc_b       = (const float*)d_in[13];
  c.v_w        = (const float*)d_in[14];
  c.v_b        = (const float*)d_in[15];
  c.wh_w       = (const float*)d_in[16];
  c.wh_b       = (const float*)d_in[17];
  c.ws_w       = (const float*)d_in[18];
  c.ws_b       = (const float*)d_in[19];
  c.wx_w       = (const float*)d_in[20];
  c.wx_b       = (const float*)d_in[21];
  c.V_w        = (const float*)d_in[22];
  c.V_b        = (const float*)d_in[23];
  c.dec_input  = (const int*)d_in[24];
  c.targets    = (const int*)d_in[25];
  c.article_inds = (const int*)d_in[26];
  c.enc_mask   = (const unsigned char*)d_in[27];

  float* p = (float*)d_ws;
  c.Gx = p;        p += TT * BB * 1024;
  c.hs = p;        p += TT * BB * 256;
  c.dec_proj = p;  p += TT * BB * 512;
  c.enc_proj = p;  p += (size_t)BB * LL * 512;
  c.WihT = p;      p += 1024 * 256;
  c.WsT = p;       p += 512 * 256;
  c.WhT = p;       p += 512 * 512;
  c.coverage = p;  p += BB * LL;
  c.scores = p;    p += 2 * BB * LL;
  c.hcbA = (unsigned short*)p; p += TT * BB * 768 / 2;
  c.pairs_m = p;   p += (size_t)640 * NPW;
  c.pairs_s = p;   p += (size_t)640 * NPW;
  c.px = p;        p += TT * BB;
  c.hws = p;       p += TT * BB;
  c.pgenA = p;     p += 640 * 16;
  c.attnA = p;     p += 640 * 16;
  c.logitA = p;    p += 640;
  c.lmA = p;       p += 640;
  c.gidxA = (int*)p; p += 640;
  c.covl_sum = p;  p += 256;
  c.hbuf_hi = (unsigned short*)p; p += 2 * 4096 / 2;
  c.hbuf_lo = (unsigned short*)p; p += 2 * 4096 / 2;
  c.bar = (unsigned*)p; p += 16;
  c.abar = (unsigned*)p; p += 512;
  c.xm = p;        p += 2 * 16 * 16;   // xms (u64) overlays xm+xs
  c.xs = p;        p += 2 * 16 * 16;
  c.xms = (unsigned long long*)c.xm;
  c.xpc = p;       p += (size_t)2 * 16 * 16 * 512;
  c.VF = (unsigned short*)p;
  size_t used_bytes = (size_t)((char*)p - (char*)d_ws);
  size_t vf_bytes = (size_t)NTILES * 12288 * 2;
  c.use_bf16 = (used_bytes + vf_bytes <= ws_size) ? 1 : 0;
  c.out = (float*)d_out;

  k_init<<<3, 256, 0, stream>>>(c);
  if (c.use_bf16) k_cvtF<<<NTILES, 256, 0, stream>>>(c.V_w, c.VF);
  k_transpose<<<dim3(8, 32), dim3(32, 8), 0, stream>>>(c.Wih, c.WihT, 1024, 256);
  k_transpose<<<dim3(8, 16), dim3(32, 8), 0, stream>>>(c.Ws_w, c.WsT, 512, 256);
  k_transpose<<<dim3(16, 16), dim3(32, 8), 0, stream>>>(c.Wh_w, c.WhT, 512, 512);
  k_gx<<<80, 256, 0, stream>>>(c);
  k_encproj<<<400, 512, 0, stream>>>(c);
  k_lstm<<<16, 256, 0, stream>>>(c);
  k_decproj<<<80, 512, 0, stream>>>(c);
  k_attn<<<256, 512, 0, stream>>>(c);
  k_vocab_all<<<98 * 16, 256, 0, stream>>>(c);
  k_final_all<<<640, 256, 0, stream>>>(c);
  k_out<<<16, 64, 0, stream>>>(c);
}

// Round 5
// 984.682 us; speedup vs baseline: 2.3561x; 1.3501x over previous
//
#include <hip/hip_runtime.h>
#include <float.h>
#include <math.h>

// Problem constants
#define BB 16
#define LL 400
#define TT 40
#define HH 256
#define EE 256
#define VOCAB 50000
#define NTILES 3128   // vocab tiles of 16 cols, 3128*16 = 50048 >= 50000
#define NPW NTILES    // pairs width

typedef __attribute__((ext_vector_type(8))) short bf16x8;
typedef __attribute__((ext_vector_type(4))) float f32x4;
typedef __attribute__((ext_vector_type(8))) unsigned short ushort8;

struct Ctx {
  // inputs
  const float *enc_states, *enc_h, *enc_c, *embed;
  const float *Wih, *Whh, *bih, *bhh;
  const float *Wh_w, *Wh_b, *Ws_w, *Ws_b;
  const float *wc_w, *wc_b, *v_w, *v_b;
  const float *wh_w, *wh_b, *ws_w, *ws_b, *wx_w, *wx_b;
  const float *V_w, *V_b;
  const int *dec_input, *targets, *article_inds;
  const unsigned char *enc_mask;
  // workspace
  float *Gx;        // [T,B,1024]
  float *hs;        // [T,B,256]
  float *dec_proj;  // [T,B,512]
  float *enc_proj;  // [B,L,512]
  float *WihT, *WsT, *WhT;
  float *coverage;  // unused (layout stability)
  float *scores;    // unused (layout stability)
  unsigned short *hcbA; // [T][96][16][8] bf16 A-fragments of concat(h,ctx)
  float *pairs_m, *pairs_s;  // [640][NPW]
  float *px, *hws;  // [T*B]
  float *pgenA, *attnA;      // [640][16] partials
  float *logitA, *lmA;       // [640]
  int *gidxA;       // [640]
  float *covl_sum;  // [16][16] partials
  unsigned short *hbuf_hi, *hbuf_lo;  // 32 KB region; hbufP (u32[2][4096]) overlays
  unsigned *bar;    // LSTM barrier (legacy)
  unsigned *abar;   // flags: [0..255] attn groups, [256..271] lstm blocks
  float *xm, *xs;   // (xms overlays these) [2][16][16] packed (m,s) as u64
  float *xpc;       // [2][16][16][512] per-block unnormalized partial context
  unsigned long long *xms;
  unsigned *hbufP;  // overlay of hbuf_hi: [2][4096] packed (hi<<16)|lo
  unsigned short *VF;  // [NTILES][24][4][16][8] bf16 V_w in B-frag order (optional)
  int use_bf16;
  float *out;       // [B]
};

__device__ __forceinline__ float sigf(float x) { return 1.f / (1.f + expf(-x)); }

// fast tanh: ~5 VALU ops via v_exp; saturates correctly
__device__ __forceinline__ float tanhfast(float x) {
  float ax = fabsf(x);
  float e = __expf(2.f * ax);
  float r = 1.f - 2.f / (e + 1.f);
  return copysignf(r, x);
}

__device__ __forceinline__ unsigned short f2bf(float x) {
  unsigned u = __builtin_bit_cast(unsigned, x);
  u = (u + 0x7FFFu + ((u >> 16) & 1u)) >> 16;
  return (unsigned short)u;
}
__device__ __forceinline__ float bf2f(unsigned short h) {
  unsigned u = ((unsigned)h) << 16;
  return __builtin_bit_cast(float, u);
}

// coherent (sc1) helpers: relaxed agent-scope atomics -> serviced at the
// device coherent point, no cache-maintenance ops, no L2 pollution.
__device__ __forceinline__ void cstore(float* p, float v) {
  __hip_atomic_store(p, v, __ATOMIC_RELAXED, __HIP_MEMORY_SCOPE_AGENT);
}
__device__ __forceinline__ float cload(const float* p) {
  return __hip_atomic_load(p, __ATOMIC_RELAXED, __HIP_MEMORY_SCOPE_AGENT);
}
__device__ __forceinline__ void cstoreu(unsigned* p, unsigned v) {
  __hip_atomic_store(p, v, __ATOMIC_RELAXED, __HIP_MEMORY_SCOPE_AGENT);
}
__device__ __forceinline__ unsigned cloadu(const unsigned* p) {
  return __hip_atomic_load(p, __ATOMIC_RELAXED, __HIP_MEMORY_SCOPE_AGENT);
}
__device__ __forceinline__ void cstore64(unsigned long long* p, unsigned long long v) {
  __hip_atomic_store(p, v, __ATOMIC_RELAXED, __HIP_MEMORY_SCOPE_AGENT);
}
__device__ __forceinline__ unsigned long long cload64(const unsigned long long* p) {
  return __hip_atomic_load(p, __ATOMIC_RELAXED, __HIP_MEMORY_SCOPE_AGENT);
}

// ---------------- init ----------------
__global__ void k_init(Ctx c) {
  int i = blockIdx.x * 256 + threadIdx.x;
  if (i == 0) *c.bar = 0u;
  if (i < 512) c.abar[i] = 0u;
  if (i < 640) {
    int t = i >> 4, b = i & 15;
    int tgt = c.targets[b * TT + t];
    c.gidxA[i] = (tgt != 0) ? tgt - 1 : 0;
  }
}

// ---------------- tiled transpose ----------------
__global__ void k_transpose(const float* __restrict__ in, float* __restrict__ out, int R, int C) {
  __shared__ float tile[32][33];
  int bx = blockIdx.x * 32, by = blockIdx.y * 32;
  int tx = threadIdx.x, ty = threadIdx.y;
  for (int i = ty; i < 32; i += 8) tile[i][tx] = in[(by + i) * C + bx + tx];
  __syncthreads();
  for (int i = ty; i < 32; i += 8) out[(bx + i) * R + by + tx] = tile[tx][i];
}

#define FMA4(acc, s, ww) { (acc).x += (s)*(ww).x; (acc).y += (s)*(ww).y; (acc).z += (s)*(ww).z; (acc).w += (s)*(ww).w; }

// ---------------- Gx: 8 batch rows per weight pass ----------------
__global__ void __launch_bounds__(256) k_gx(Ctx c) {
  int t = blockIdx.x >> 1, hh = blockIdx.x & 1;
  int tid = threadIdx.x;
  __shared__ int tok_s[8];
  __shared__ float x[8][256];
  if (tid < 8) tok_s[tid] = c.dec_input[(hh * 8 + tid) * TT + t];
  __syncthreads();
  for (int u = tid; u < 2048; u += 256) {
    int r = u >> 8, k = u & 255;
    x[r][k] = c.embed[(size_t)tok_s[r] * 256 + k];
  }
  __syncthreads();
  const float4* WT4 = (const float4*)c.WihT;
  float4 bias = ((const float4*)c.bih)[tid];
  float4 b2 = ((const float4*)c.bhh)[tid];
  bias.x += b2.x; bias.y += b2.y; bias.z += b2.z; bias.w += b2.w;
  float4 acc[8];
#pragma unroll
  for (int r = 0; r < 8; ++r) acc[r] = bias;
  for (int k = 0; k < 256; k += 4) {
    float4 w0 = WT4[(k + 0) * 256 + tid];
    float4 w1 = WT4[(k + 1) * 256 + tid];
    float4 w2 = WT4[(k + 2) * 256 + tid];
    float4 w3 = WT4[(k + 3) * 256 + tid];
#pragma unroll
    for (int r = 0; r < 8; ++r) {
      float4 e4 = *(const float4*)&x[r][k];
      FMA4(acc[r], e4.x, w0); FMA4(acc[r], e4.y, w1);
      FMA4(acc[r], e4.z, w2); FMA4(acc[r], e4.w, w3);
    }
  }
#pragma unroll
  for (int r = 0; r < 8; ++r)
    ((float4*)c.Gx)[(size_t)(t * 16 + hh * 8 + r) * 256 + tid] = acc[r];
  {
    int r = tid >> 5, l32 = tid & 31;
    float p = 0.f;
#pragma unroll
    for (int i = 0; i < 8; ++i) {
      int k = l32 + 32 * i;
      p += x[r][k] * c.wx_w[k];
    }
    for (int off = 1; off < 32; off <<= 1) p += __shfl_xor(p, off, 32);
    if (l32 == 0) c.px[t * 16 + hh * 8 + r] = p;
  }
}

// ---------------- fused: LSTM (16 blocks) + enc_proj (400) + V_w cvt (3128) ----------------
// LSTM uses only 16 CUs for its whole barrier-bound runtime; the other roles
// fill the remaining 240 CUs for free. LSTM h-exchange uses the sc1-relaxed
// publish + flag-poll pattern (no threadfence/acquire -> no L2 invalidates).
__global__ void __launch_bounds__(512) k_fused3(Ctx c) {
  __shared__ union SmemU {
    struct { unsigned short hAhi[4096], hAlo[4096]; float gs[4][16][16]; } L;
    float es[16][512];
    unsigned short tile[16][800];
  } sm;
  int bid = blockIdx.x;
  int tid = threadIdx.x;
  if (bid < 16) {
    // ================= LSTM role (tid<256 active; all 512 hit barriers) ========
    int w = bid;
    int g = (tid >> 6) & 3, lane = tid & 63;
    int n = lane & 15, q = lane >> 4;
    bf16x8 Bhi[8], Blo[8];
    float creg = 0.f;
    int bu = (tid >> 4) & 15, ju = tid & 15;
    if (tid < 256) {
      const float* wr = c.Whh + (size_t)(g * 256 + w * 16 + n) * 256;
#pragma unroll
      for (int kc = 0; kc < 8; ++kc) {
        const float* p8 = wr + kc * 32 + q * 8;
#pragma unroll
        for (int j = 0; j < 8; ++j) {
          float x = p8[j];
          unsigned short hi = f2bf(x);
          unsigned short lo = f2bf(x - bf2f(hi));
          Bhi[kc][j] = (short)hi; Blo[kc][j] = (short)lo;
        }
      }
      creg = c.enc_c[bu * 256 + w * 16 + ju];
    }
    for (int idx = tid; idx < 4096; idx += 512) {
      int b = idx >> 8, k = idx & 255;
      float x = c.enc_h[idx];
      unsigned short hi = f2bf(x);
      unsigned short lo = f2bf(x - bf2f(hi));
      int pos = (((k >> 5) * 4 + ((k >> 3) & 3)) * 16 + b) * 8 + (k & 7);
      sm.L.hAhi[pos] = hi; sm.L.hAlo[pos] = lo;
    }
    __syncthreads();
    const bf16x8* Ahi = (const bf16x8*)sm.L.hAhi;
    const bf16x8* Alo = (const bf16x8*)sm.L.hAlo;
    int col = g * 256 + w * 16 + n;
    for (int t = 0; t < TT; ++t) {
      if (tid < 256) {
        const float* gxp = c.Gx + (size_t)(t * 16) * 1024 + col;
        f32x4 acc;
        acc[0] = gxp[(q * 4 + 0) * 1024]; acc[1] = gxp[(q * 4 + 1) * 1024];
        acc[2] = gxp[(q * 4 + 2) * 1024]; acc[3] = gxp[(q * 4 + 3) * 1024];
#pragma unroll
        for (int kc = 0; kc < 8; ++kc) {
          bf16x8 ah = Ahi[(kc * 4 + q) * 16 + n];
          bf16x8 al = Alo[(kc * 4 + q) * 16 + n];
          acc = __builtin_amdgcn_mfma_f32_16x16x32_bf16(ah, Bhi[kc], acc, 0, 0, 0);
          acc = __builtin_amdgcn_mfma_f32_16x16x32_bf16(al, Bhi[kc], acc, 0, 0, 0);
          acc = __builtin_amdgcn_mfma_f32_16x16x32_bf16(ah, Blo[kc], acc, 0, 0, 0);
        }
#pragma unroll
        for (int r = 0; r < 4; ++r) sm.L.gs[g][q * 4 + r][n] = acc[r];
      }
      __syncthreads();
      int par = (t + 1) & 1;
      if (tid < 256) {
        float ig = sm.L.gs[0][bu][ju], fg = sm.L.gs[1][bu][ju];
        float gg = sm.L.gs[2][bu][ju], og = sm.L.gs[3][bu][ju];
        creg = sigf(fg) * creg + sigf(ig) * tanhf(gg);
        float hv = sigf(og) * tanhf(creg);
        int j = w * 16 + ju;
        c.hs[(t * 16 + bu) * 256 + j] = hv;
        unsigned short hi = f2bf(hv);
        unsigned short lo = f2bf(hv - bf2f(hi));
        int pos = (((j >> 5) * 4 + ((j >> 3) & 3)) * 16 + bu) * 8 + (j & 7);
        cstoreu(&c.hbufP[par * 4096 + pos], ((unsigned)hi << 16) | lo);
      }
      asm volatile("s_waitcnt vmcnt(0)" ::: "memory");
      __syncthreads();
      if (tid == 0) cstoreu(&c.abar[256 + w], (unsigned)(t + 1));
      if (tid < 16) {
        while (cloadu(&c.abar[256 + tid]) < (unsigned)(t + 1))
          __builtin_amdgcn_s_sleep(1);
      }
      __syncthreads();
      if (t < TT - 1) {
        for (int idx = tid; idx < 4096; idx += 512) {
          unsigned v = cloadu(&c.hbufP[par * 4096 + idx]);
          sm.L.hAhi[idx] = (unsigned short)(v >> 16);
          sm.L.hAlo[idx] = (unsigned short)(v & 0xFFFFu);
        }
        __syncthreads();
      }
    }
  } else if (bid < 416) {
    // ================= enc_proj role: 16 rows per weight pass ================
    int r0 = bid - 16;
    int b = r0 / 25, lt = (r0 % 25) * 16;
    for (int u = tid; u < 8192; u += 512)
      sm.es[u >> 9][u & 511] = c.enc_states[(size_t)(b * LL + lt) * 512 + u];
    __syncthreads();
    float bias = c.Wh_b[tid];
    float acc[16];
#pragma unroll
    for (int r = 0; r < 16; ++r) acc[r] = bias;
    for (int k = 0; k < 512; k += 4) {
      float w0 = c.WhT[(k + 0) * 512 + tid];
      float w1 = c.WhT[(k + 1) * 512 + tid];
      float w2 = c.WhT[(k + 2) * 512 + tid];
      float w3 = c.WhT[(k + 3) * 512 + tid];
#pragma unroll
      for (int r = 0; r < 16; ++r) {
        float4 e4 = *(const float4*)&sm.es[r][k];
        acc[r] += e4.x * w0 + e4.y * w1 + e4.z * w2 + e4.w * w3;
      }
    }
#pragma unroll
    for (int r = 0; r < 16; ++r)
      c.enc_proj[(size_t)(b * LL + lt + r) * 512 + tid] = acc[r];
  } else {
    // ================= V_w fp32 -> bf16 (B-frag order) role ==================
    int nt = bid - 416;
    for (int u = tid; u < 3072; u += 512) {
      int rr = u / 192, cc = u % 192;
      int v = nt * 16 + rr;
      float4 x = {0.f, 0.f, 0.f, 0.f};
      if (v < VOCAB) x = ((const float4*)(c.V_w + (size_t)v * 768))[cc];
      unsigned short* d = &sm.tile[rr][cc * 4];
      d[0] = f2bf(x.x); d[1] = f2bf(x.y); d[2] = f2bf(x.z); d[3] = f2bf(x.w);
    }
    __syncthreads();
    ushort8* dst = (ushort8*)(c.VF + (size_t)nt * 12288);
    for (int u = tid; u < 1536; u += 512) {
      int n = u & 15, kq = u >> 4;
      const unsigned short* s = &sm.tile[n][kq * 8];
      ushort8 o;
#pragma unroll
      for (int j = 0; j < 8; ++j) o[j] = s[j];
      dst[u] = o;
    }
  }
}

// ---------------- dec_proj: 8 rows per weight pass ----------------
__global__ void __launch_bounds__(512) k_decproj(Ctx c) {
  int t = blockIdx.x >> 1, hh = blockIdx.x & 1;
  int tid = threadIdx.x;
  __shared__ float h[8][256];
  for (int u = tid; u < 2048; u += 512)
    h[u >> 8][u & 255] = c.hs[(size_t)(t * 16 + hh * 8 + (u >> 8)) * 256 + (u & 255)];
  __syncthreads();
  float bias = c.Ws_b[tid];
  float acc[8];
#pragma unroll
  for (int r = 0; r < 8; ++r) acc[r] = bias;
  for (int k = 0; k < 256; k += 4) {
    float w0 = c.WsT[(k + 0) * 512 + tid];
    float w1 = c.WsT[(k + 1) * 512 + tid];
    float w2 = c.WsT[(k + 2) * 512 + tid];
    float w3 = c.WsT[(k + 3) * 512 + tid];
#pragma unroll
    for (int r = 0; r < 8; ++r) {
      float4 e4 = *(const float4*)&h[r][k];
      acc[r] += e4.x * w0 + e4.y * w1 + e4.z * w2 + e4.w * w3;
    }
  }
#pragma unroll
  for (int r = 0; r < 8; ++r)
    c.dec_proj[(size_t)(t * 16 + hh * 8 + r) * 512 + tid] = acc[r];
  {
    int wv = tid >> 6, lane = tid & 63;
    float p = 0.f;
#pragma unroll
    for (int i = 0; i < 4; ++i) {
      int k = lane + 64 * i;
      p += h[wv][k] * c.ws_w[k];
    }
    for (int off = 1; off < 64; off <<= 1) p += __shfl_xor(p, off, 64);
    if (lane == 0) c.hws[t * 16 + hh * 8 + wv] = p;
  }
}

// ---------------- persistent fused attention loop (unchanged, proven) ----------------
__global__ void __launch_bounds__(512, 2) k_attn(Ctx c) {
  __shared__ float ep_s[25 * 512];
  __shared__ float wcw_s[512], wcb_s[512], vw_s[512], dp_s[512];
  __shared__ float sc_s[32];
  __shared__ float psc_s[32];
  __shared__ float xf_s[16];
  __shared__ float ctxred[16][32];
  __shared__ float cov_s[25];
  __shared__ int idx_s[25];
  __shared__ unsigned char msk_s[32];
  __shared__ float mb_s, sb_s, S_s;
  int tid = threadIdx.x;
  int b = blockIdx.x >> 4;
  int blk = blockIdx.x & 15;
  int l0 = blk * 25;
  int wv = tid >> 6, lane = tid & 63;
  const float* epb = c.enc_proj + ((size_t)b * LL + l0) * 512;
  const float* esb = c.enc_states + ((size_t)b * LL + l0) * 512;
  for (int i = tid; i < 12800; i += 512) ep_s[i] = epb[i];
  wcw_s[tid] = c.wc_w[tid];
  wcb_s[tid] = c.wc_b[tid];
  vw_s[tid]  = c.v_w[tid];
  if (tid < 25) {
    cov_s[tid] = 0.f;
    unsigned char m = c.enc_mask[b * LL + l0 + tid];
    msk_s[tid] = m;
    idx_s[tid] = m ? 0 : (c.article_inds[b * LL + l0 + tid] - 1);
  }
  float covl_loc = 0.f;
  float vb = c.v_b[0];
  float dpr = c.dec_proj[(size_t)(0 * 16 + b) * 512 + tid];
  __syncthreads();
  for (int t = 0; t < TT; ++t) {
    int par = t & 1;
    dp_s[tid] = dpr;
    __syncthreads();
    {
      int r0 = wv, r1 = wv + 8, r2 = wv + 16;
      bool v3 = (wv == 0);
      float c0 = cov_s[r0], c1 = cov_s[r1], c2 = cov_s[r2], c3 = cov_s[24];
      const float *e0 = ep_s + r0 * 512, *e1 = ep_s + r1 * 512;
      const float *e2 = ep_s + r2 * 512, *e3 = ep_s + 24 * 512;
      float a0 = 0.f, a1 = 0.f, a2 = 0.f, a3 = 0.f;
#pragma unroll
      for (int i = 0; i < 8; ++i) {
        int j = lane + 64 * i;
        float base = dp_s[j] + wcb_s[j];
        float ww = wcw_s[j], vv = vw_s[j];
        a0 += tanhfast(e0[j] + base + c0 * ww) * vv;
        a1 += tanhfast(e1[j] + base + c1 * ww) * vv;
        a2 += tanhfast(e2[j] + base + c2 * ww) * vv;
        if (v3) a3 += tanhfast(e3[j] + base + c3 * ww) * vv;
      }
#pragma unroll
      for (int off = 1; off < 64; off <<= 1) {
        a0 += __shfl_xor(a0, off, 64);
        a1 += __shfl_xor(a1, off, 64);
        a2 += __shfl_xor(a2, off, 64);
        a3 += __shfl_xor(a3, off, 64);
      }
      if (lane == 0) {
        sc_s[r0] = a0 + vb; sc_s[r1] = a1 + vb; sc_s[r2] = a2 + vb;
        if (v3) sc_s[24] = a3 + vb;
      }
    }
    __syncthreads();
    if (tid < 32) {
      bool ok = (tid < 25) && !msk_s[tid & 31];
      float s = ok ? sc_s[tid] : -FLT_MAX;
      float m = s;
      for (int off = 1; off < 32; off <<= 1) m = fmaxf(m, __shfl_xor(m, off, 32));
      float pv = ok ? __expf(s - m) : 0.f;
      psc_s[tid] = pv;
      float sm = pv;
      for (int off = 1; off < 32; off <<= 1) sm += __shfl_xor(sm, off, 32);
      if (tid == 0) { mb_s = m; sb_s = sm; }
    }
    __syncthreads();
    float pc = 0.f;
#pragma unroll
    for (int l = 0; l < 25; ++l) pc += psc_s[l] * esb[(size_t)l * 512 + tid];
    {
      size_t xb = ((size_t)(par * 16 + b) * 16 + blk) * 512;
      cstore(&c.xpc[xb + tid], pc);
      if (tid == 0) {
        unsigned long long pk = ((unsigned long long)__builtin_bit_cast(unsigned, sb_s) << 32)
                              | __builtin_bit_cast(unsigned, mb_s);
        cstore64(&c.xms[(par * 16 + b) * 16 + blk], pk);
      }
    }
    asm volatile("s_waitcnt vmcnt(0)" ::: "memory");
    if (blk == 0 && tid < 256) {
      float hv = c.hs[(size_t)(t * 16 + b) * 256 + tid];
      c.hcbA[(size_t)t * 12288 + (tid >> 3) * 128 + b * 8 + (tid & 7)] = f2bf(hv);
    }
    {
      int tn = (t + 1 < TT) ? t + 1 : t;
      dpr = c.dec_proj[(size_t)(tn * 16 + b) * 512 + tid];
    }
    __syncthreads();
    if (tid == 0) cstoreu(&c.abar[b * 16 + blk], (unsigned)(t + 1));
    if (tid < 16) {
      while (cloadu(&c.abar[b * 16 + tid]) < (unsigned)(t + 1))
        __builtin_amdgcn_s_sleep(1);
    }
    __syncthreads();
    float pcv = cload(&c.xpc[((size_t)(par * 16 + b) * 16 + (tid >> 5)) * 512 + blk * 32 + (tid & 31)]);
    if (tid < 16) {
      unsigned long long pk = cload64(&c.xms[(par * 16 + b) * 16 + tid]);
      float m = __builtin_bit_cast(float, (unsigned)(pk & 0xFFFFFFFFu));
      float s = __builtin_bit_cast(float, (unsigned)(pk >> 32));
      float M = m;
      for (int off = 1; off < 16; off <<= 1) M = fmaxf(M, __shfl_xor(M, off, 16));
      float f = __expf(m - M);
      float z = s * f;
      for (int off = 1; off < 16; off <<= 1) z += __shfl_xor(z, off, 16);
      xf_s[tid] = f;
      if (tid == 0) S_s = z;
    }
    __syncthreads();
    ctxred[tid >> 5][tid & 31] = pcv * xf_s[tid >> 5];
    if (tid < 32) {
      float cvl = 0.f, mct = 0.f;
      if (tid < 25) {
        float a = psc_s[tid] * xf_s[blk] / S_s;
        float nc = cov_s[tid] + a;
        cov_s[tid] = nc;
        cvl = fminf(nc, a);
        int gidx = c.gidxA[t * 16 + b];
        mct = (idx_s[tid] == gidx) ? a : 0.f;
      }
      for (int off = 1; off < 32; off <<= 1) {
        cvl += __shfl_xor(cvl, off, 32);
        mct += __shfl_xor(mct, off, 32);
      }
      if (tid == 0) {
        covl_loc += cvl;
        c.attnA[(size_t)(t * 16 + b) * 16 + blk] = mct;
      }
    }
    __syncthreads();
    if (tid < 32) {
      float cx = 0.f;
#pragma unroll
      for (int r = 0; r < 16; ++r) cx += ctxred[r][tid];
      cx /= S_s;
      int jj = 256 + blk * 32 + tid;
      c.hcbA[(size_t)t * 12288 + (jj >> 3) * 128 + b * 8 + (jj & 7)] = f2bf(cx);
      float pp = cx * c.wh_w[blk * 32 + tid];
      for (int off = 1; off < 32; off <<= 1) pp += __shfl_xor(pp, off, 32);
      if (tid == 0) c.pgenA[(size_t)(t * 16 + b) * 16 + blk] = pp;
    }
    __syncthreads();
  }
  if (tid == 0) c.covl_sum[b * 16 + blk] = covl_loc;
}

// ---------------- one-shot vocab GEMM: D[10], (256,4), same-XCD t-group pairing,
// A-fragments staged in LDS (shared by 4 waves, double-buffered per kc) ----------------
// grid 3136 = 98*32; cg=(bid>>5)*8+(bid&7) so the 4 t-groups sharing a VF tile
// land at stride-8 block indices -> same XCD, adjacent dispatch -> VF read ~once.
__global__ void __launch_bounds__(256, 4) k_vocab_all(Ctx c) {
  __shared__ bf16x8 als[2][640];   // [kc parity][i*64 + lane], 20.5 KB
  int tid = threadIdx.x;
  int wv = tid >> 6, lane = tid & 63;
  int n = lane & 15, q = lane >> 4;
  int bid = blockIdx.x;
  int cg = (bid >> 5) * 8 + (bid & 7);   // 0..783
  int tg = (bid >> 3) & 3;               // 0..3
  int nt = cg * 4 + wv;
  int ntc = (nt < NTILES) ? nt : NTILES - 1;
  int col = nt * 16 + n;
  bool vld = (nt < NTILES) && (col < VOCAB);
  int colc = (col < VOCAB) ? col : VOCAB - 1;
  float vb = c.V_b[colc];
  int t0 = tg * 10;
  f32x4 D[10];
#pragma unroll
  for (int i = 0; i < 10; ++i) D[i] = (f32x4){0.f, 0.f, 0.f, 0.f};
  const bf16x8* A8 = (const bf16x8*)c.hcbA;
  size_t abase = (size_t)t0 * 1536;      // frag units; + i*1536 + kc*64 + lane
  if (c.use_bf16) {
    const bf16x8* BF = (const bf16x8*)c.VF;
    size_t bbase = (size_t)ntc * 1536 + q * 16 + n;
    for (int u = tid; u < 640; u += 256)
      als[0][u] = A8[abase + (size_t)(u >> 6) * 1536 + (u & 63)];
    __syncthreads();
    for (int kc = 0; kc < 24; ++kc) {
      int pr = kc & 1;
      if (kc < 23) {
        for (int u = tid; u < 640; u += 256)
          als[pr ^ 1][u] = A8[abase + (size_t)(u >> 6) * 1536 + (kc + 1) * 64 + (u & 63)];
      }
      bf16x8 B = BF[bbase + kc * 64];
#pragma unroll
      for (int i = 0; i < 10; ++i)
        D[i] = __builtin_amdgcn_mfma_f32_16x16x32_bf16(als[pr][i * 64 + lane], B, D[i], 0, 0, 0);
      __syncthreads();
    }
  } else {
    size_t abase2 = abase + q * 16 + n;
    for (int kc = 0; kc < 24; ++kc) {
      const float4* vr = (const float4*)(c.V_w + (size_t)colc * 768 + kc * 32 + q * 8);
      float4 b0 = vr[0], b1 = vr[1];
      bf16x8 B;
      B[0] = (short)f2bf(b0.x); B[1] = (short)f2bf(b0.y); B[2] = (short)f2bf(b0.z); B[3] = (short)f2bf(b0.w);
      B[4] = (short)f2bf(b1.x); B[5] = (short)f2bf(b1.y); B[6] = (short)f2bf(b1.z); B[7] = (short)f2bf(b1.w);
#pragma unroll
      for (int i = 0; i < 10; ++i) {
        bf16x8 a = A8[abase2 + (size_t)i * 1536 + kc * 64];
        D[i] = __builtin_amdgcn_mfma_f32_16x16x32_bf16(a, B, D[i], 0, 0, 0);
      }
    }
  }
#pragma unroll
  for (int i = 0; i < 10; ++i) {
    int t = t0 + i;
#pragma unroll
    for (int r = 0; r < 4; ++r) {
      int b = q * 4 + r;
      int rw = t * 16 + b;
      float lg = D[i][r] + vb;
      if (vld && col == c.gidxA[rw]) c.logitA[rw] = lg;
      float m_ = vld ? lg : -FLT_MAX;
      float s_ = vld ? 1.f : 0.f;
#pragma unroll
      for (int off = 1; off < 16; off <<= 1) {
        float om = __shfl_xor(m_, off, 16);
        float os = __shfl_xor(s_, off, 16);
        float Mm = fmaxf(m_, om);
        s_ = s_ * __expf(m_ - Mm) + os * __expf(om - Mm);
        m_ = Mm;
      }
      if (n == 0 && nt < NTILES) {
        c.pairs_m[(size_t)rw * NPW + nt] = m_;
        c.pairs_s[(size_t)rw * NPW + nt] = s_;
      }
    }
  }
}

// ---------------- per-(t,b) loss from pairs ----------------
__global__ void k_final_all(Ctx c) {
  int row = blockIdx.x;
  int tid = threadIdx.x;
  __shared__ float red[256];
  float m = -FLT_MAX;
  for (int i = tid; i < NPW; i += 256) m = fmaxf(m, c.pairs_m[(size_t)row * NPW + i]);
  red[tid] = m; __syncthreads();
  for (int s = 128; s > 0; s >>= 1) { if (tid < s) red[tid] = fmaxf(red[tid], red[tid + s]); __syncthreads(); }
  float M = red[0]; __syncthreads();
  float z = 0.f;
  for (int i = tid; i < NPW; i += 256)
    z += c.pairs_s[(size_t)row * NPW + i] * __expf(c.pairs_m[(size_t)row * NPW + i] - M);
  red[tid] = z; __syncthreads();
  for (int s = 128; s > 0; s >>= 1) { if (tid < s) red[tid] += red[tid + s]; __syncthreads(); }
  if (tid == 0) {
    int t = row >> 4, b = row & 15;
    int tgt = c.targets[b * TT + t];
    float lm = 0.f;
    if (tgt != 0) {
      float pgs = 0.f, ats = 0.f;
#pragma unroll
      for (int i = 0; i < 16; ++i) {
        pgs += c.pgenA[(size_t)row * 16 + i];
        ats += c.attnA[(size_t)row * 16 + i];
      }
      float pg = sigf(pgs + c.wh_b[0] + c.hws[row] + c.ws_b[0] + c.px[row] + c.wx_b[0]);
      float p = __expf(c.logitA[row] - M) / red[0];
      lm = -logf(pg * p + (1.f - pg) * ats);
    }
    c.lmA[row] = lm;
  }
}

// ---------------- output ----------------
__global__ void k_out(Ctx c) {
  int b = blockIdx.x, tid = threadIdx.x;
  float lm = (tid < TT) ? c.lmA[tid * 16 + b] : 0.f;
  float dl = (tid < TT && c.dec_input[b * TT + tid] > 0) ? 1.f : 0.f;
  float cv = (tid < 16) ? c.covl_sum[b * 16 + tid] : 0.f;
  for (int off = 1; off < 64; off <<= 1) {
    lm += __shfl_xor(lm, off, 64);
    dl += __shfl_xor(dl, off, 64);
    cv += __shfl_xor(cv, off, 64);
  }
  if (tid == 0) c.out[b] = lm / dl + cv / dl;
}

extern "C" void kernel_launch(void* const* d_in, const int* in_sizes, int n_in,
                              void* d_out, int out_size, void* d_ws, size_t ws_size,
                              hipStream_t stream) {
  Ctx c;
  c.enc_states = (const float*)d_in[0];
  c.enc_h      = (const float*)d_in[1];
  c.enc_c      = (const float*)d_in[2];
  c.embed      = (const float*)d_in[3];
  c.Wih        = (const float*)d_in[4];
  c.Whh        = (const float*)d_in[5];
  c.bih        = (const float*)d_in[6];
  c.bhh        = (const float*)d_in[7];
  c.Wh_w       = (const float*)d_in[8];
  c.Wh_b       = (const float*)d_in[9];
  c.Ws_w       = (const float*)d_in[10];
  c.Ws_b       = (const float*)d_in[11];
  c.wc_w       = (const float*)d_in[12];
  c.wc_b       = (const float*)d_in[13];
  c.v_w        = (const float*)d_in[14];
  c.v_b        = (const float*)d_in[15];
  c.wh_w       = (const float*)d_in[16];
  c.wh_b       = (const float*)d_in[17];
  c.ws_w       = (const float*)d_in[18];
  c.ws_b       = (const float*)d_in[19];
  c.wx_w       = (const float*)d_in[20];
  c.wx_b       = (const float*)d_in[21];
  c.V_w        = (const float*)d_in[22];
  c.V_b        = (const float*)d_in[23];
  c.dec_input  = (const int*)d_in[24];
  c.targets    = (const int*)d_in[25];
  c.article_inds = (const int*)d_in[26];
  c.enc_mask   = (const unsigned char*)d_in[27];

  float* p = (float*)d_ws;
  c.Gx = p;        p += TT * BB * 1024;
  c.hs = p;        p += TT * BB * 256;
  c.dec_proj = p;  p += TT * BB * 512;
  c.enc_proj = p;  p += (size_t)BB * LL * 512;
  c.WihT = p;      p += 1024 * 256;
  c.WsT = p;       p += 512 * 256;
  c.WhT = p;       p += 512 * 512;
  c.coverage = p;  p += BB * LL;
  c.scores = p;    p += 2 * BB * LL;
  c.hcbA = (unsigned short*)p; p += TT * BB * 768 / 2;
  c.pairs_m = p;   p += (size_t)640 * NPW;
  c.pairs_s = p;   p += (size_t)640 * NPW;
  c.px = p;        p += TT * BB;
  c.hws = p;       p += TT * BB;
  c.pgenA = p;     p += 640 * 16;
  c.attnA = p;     p += 640 * 16;
  c.logitA = p;    p += 640;
  c.lmA = p;       p += 640;
  c.gidxA = (int*)p; p += 640;
  c.covl_sum = p;  p += 256;
  c.hbuf_hi = (unsigned short*)p; p += 2 * 4096 / 2;
  c.hbuf_lo = (unsigned short*)p; p += 2 * 4096 / 2;
  c.hbufP = (unsigned*)c.hbuf_hi;   // overlay: [2][4096] u32 = 32 KB
  c.bar = (unsigned*)p; p += 16;
  c.abar = (unsigned*)p; p += 512;
  c.xm = p;        p += 2 * 16 * 16;   // xms (u64) overlays xm+xs
  c.xs = p;        p += 2 * 16 * 16;
  c.xms = (unsigned long long*)c.xm;
  c.xpc = p;       p += (size_t)2 * 16 * 16 * 512;
  c.VF = (unsigned short*)p;
  size_t used_bytes = (size_t)((char*)p - (char*)d_ws);
  size_t vf_bytes = (size_t)NTILES * 12288 * 2;
  c.use_bf16 = (used_bytes + vf_bytes <= ws_size) ? 1 : 0;
  c.out = (float*)d_out;

  k_init<<<3, 256, 0, stream>>>(c);
  k_transpose<<<dim3(8, 32), dim3(32, 8), 0, stream>>>(c.Wih, c.WihT, 1024, 256);
  k_transpose<<<dim3(8, 16), dim3(32, 8), 0, stream>>>(c.Ws_w, c.WsT, 512, 256);
  k_transpose<<<dim3(16, 16), dim3(32, 8), 0, stream>>>(c.Wh_w, c.WhT, 512, 512);
  k_gx<<<80, 256, 0, stream>>>(c);
  int fused_grid = 416 + (c.use_bf16 ? NTILES : 0);
  k_fused3<<<fused_grid, 512, 0, stream>>>(c);
  k_decproj<<<80, 512, 0, stream>>>(c);
  k_attn<<<256, 512, 0, stream>>>(c);
  k_vocab_all<<<98 * 32, 256, 0, stream>>>(c);
  k_final_all<<<640, 256, 0, stream>>>(c);
  k_out<<<16, 64, 0, stream>>>(c);
}